// Round 11
// baseline (281.358 us; speedup 1.0000x reference)
//
#include <hip/hip_runtime.h>
#include <math.h>

#define DIM 24
#define HID 256
#define NLO 276
#define NSAMP 4096
// output layout: M [4096*576] | c [4096*24] | g [4096*24]
#define C_OFF 2359296
#define G_OFF 2457600

// workspace layout (float offsets)
#define OFF_W2FH 0          // bf16 hi, W2 MFMA-A frags (65536 sh)   32768 f
#define OFF_W2FL 32768      // bf16 lo
#define OFF_WEFH 65536      // bf16 hi, [WLd;WLo;0] frags (81920 sh) 40960 f
#define OFF_WEFL 106496
#define OFF_W1H16 147456    // f16 hi, W1 frags (8192 sh)            4096 f
#define OFF_W1L16 151552
#define OFF_W2H16 155648    // f16 hi, W2 frags (65536 sh)           32768 f
#define OFF_W2L16 188416
#define OFF_WHH16 221184    // f16 hi, heads (Ld|G|Lo|0) frags       43008 f
#define OFF_WHL16 264192
// transposed per-sample fields [field][4096]
#define OFF_MSKT 307200     // 16 u32 words x 4096
#define OFF_SIGT 372736     // 24 x 4096
#define OFF_LDT  471040     // 24 x 4096
#define OFF_UT   569344     // 24 x 4096
#define OFF_LOT  667648     // 276 x 4096

typedef __attribute__((ext_vector_type(8))) short bf16x8;
typedef __attribute__((ext_vector_type(8))) _Float16 f16x8;
typedef __attribute__((ext_vector_type(4))) float f32x4;

__device__ __forceinline__ float leaky(float x){ return x > 0.f ? x : 0.01f*x; }
__device__ __forceinline__ unsigned short f2b(float f){           // fp32 -> bf16 RNE
  unsigned u = __float_as_uint(f);
  return (unsigned short)((u + 0x7FFFu + ((u >> 16) & 1u)) >> 16);
}
__device__ __forceinline__ float b2f(unsigned short h){ return __uint_as_float(((unsigned)h) << 16); }
__device__ __forceinline__ void f2h2(float v, unsigned short* hi, unsigned short* lo){
  _Float16 h = (_Float16)v;
  _Float16 l = (_Float16)((v - (float)h) * 4096.f);
  *hi = *(unsigned short*)&h; *lo = *(unsigned short*)&l;
}

// ---------------- Kernel 0: fragment packing ----------------
__global__ __launch_bounds__(256) void k0_prep(
    const float* __restrict__ W1, const float* __restrict__ W2,
    const float* __restrict__ WG, const float* __restrict__ WLd,
    const float* __restrict__ WLo, float* __restrict__ ws)
{
  const int tid = blockIdx.x*256 + threadIdx.x;
  const int nth = gridDim.x*256;
  unsigned short* W2FH = (unsigned short*)(ws + OFF_W2FH);
  unsigned short* W2FL = (unsigned short*)(ws + OFF_W2FL);
  for (int e = tid; e < 65536; e += nth){
    int j=e&7, l=(e>>3)&63, kb=(e>>9)&7, mt=e>>12;
    int m = mt*16+(l&15), k = kb*32+((l>>4)&3)*8+j;
    float v = W2[m*256+k];
    unsigned short h = f2b(v);
    W2FH[e]=h; W2FL[e]=f2b(v-b2f(h));
  }
  unsigned short* WEFH = (unsigned short*)(ws + OFF_WEFH);
  unsigned short* WEFL = (unsigned short*)(ws + OFF_WEFL);
  for (int e = tid; e < 81920; e += nth){
    int j=e&7, l=(e>>3)&63, kb=(e>>9)&7, mt=e>>12;
    int r = mt*16+(l&15), k = kb*32+((l>>4)&3)*8+j;
    float v = 0.f;
    if (r < 24) v = WLd[r*256+k]; else if (r < 300) v = WLo[(r-24)*256+k];
    unsigned short h = f2b(v);
    WEFH[e]=h; WEFL[e]=f2b(v-b2f(h));
  }
  unsigned short* W1H = (unsigned short*)(ws + OFF_W1H16);
  unsigned short* W1L = (unsigned short*)(ws + OFF_W1L16);
  for (int e = tid; e < 8192; e += nth){
    int j=e&7, l=(e>>3)&63, mt=e>>9;
    int m = mt*16+(l&15), k = ((l>>4)&3)*8+j;
    float v = (k < 24) ? W1[m*24+k] : 0.f;
    f2h2(v, &W1H[e], &W1L[e]);
  }
  unsigned short* W2H = (unsigned short*)(ws + OFF_W2H16);
  unsigned short* W2L = (unsigned short*)(ws + OFF_W2L16);
  for (int e = tid; e < 65536; e += nth){
    int j=e&7, l=(e>>3)&63, kb=(e>>9)&7, mt=e>>12;
    int m = mt*16+(l&15), k = kb*32+((l>>4)&3)*8+j;
    f2h2(W2[m*256+k], &W2H[e], &W2L[e]);
  }
  unsigned short* WHH = (unsigned short*)(ws + OFF_WHH16);
  unsigned short* WHL = (unsigned short*)(ws + OFF_WHL16);
  for (int e = tid; e < 86016; e += nth){
    int j=e&7, l=(e>>3)&63, kb=(e>>9)&7, mt=e>>12;
    int rr = mt*16+(l&15), k = kb*32+((l>>4)&3)*8+j;
    float v = 0.f;
    if (rr < 24) v = WLd[rr*256+k];
    else if (rr < 48) v = WG[(rr-24)*256+k];
    else if (rr < 324) v = WLo[(rr-48)*256+k];
    f2h2(v, &WHH[e], &WHL[e]);
  }
}

// ---------------- Kernel 1: MFMA forward + L/M/u (4 samples/block, 1024 blocks) ----------------
__global__ __launch_bounds__(256) void k1_fwd(
    const float* __restrict__ q, const float* __restrict__ qd_g,
    const float* __restrict__ b1, const float* __restrict__ b2,
    const float* __restrict__ bG, const float* __restrict__ bLd,
    const float* __restrict__ bLo, float* __restrict__ ws,
    float* __restrict__ out)
{
  const int s0 = blockIdx.x*4, t = threadIdx.x;
  const int w = t>>6, l = t&63, l15 = l&15, l4g = (l>>4)&3;
  unsigned* MSKT = (unsigned*)(ws + OFF_MSKT);
  float* SIGT = ws + OFF_SIGT;
  float* LDT  = ws + OFF_LDT;
  float* UT   = ws + OFF_UT;
  float* LOT  = ws + OFF_LOT;

  // pool sized for 16 N-columns of LDS reads (rows >=4 are never written; their
  // garbage feeds MFMA columns that are never stored)
  __shared__ __align__(16) unsigned short pool[8448];  // BQ -> BH2|BL2
  __shared__ unsigned char mb[4][64];
  __shared__ float qd_s[4][24];
  __shared__ float Lsm[4][600];          // per-sample L, stride 25
  unsigned short* BQH = pool;            // [4][40] f16 (reads span 16 rows)
  unsigned short* BQL = BQH + 160;
  unsigned short* BH2 = pool;            // [4][264] f16 (reads span 16 rows)
  unsigned short* BL2 = BH2 + 4224;

  for (int f = t; f < 96; f += 256){
    float v = q[s0*24 + f];
    int n = f/24, k = f%24;
    f2h2(v, &BQH[n*40+k], &BQL[n*40+k]);
    ((float*)qd_s)[f] = qd_g[s0*24 + f];
  }
  if (t < 32){ int n = t>>3, k = 24 + (t&7); BQH[n*40+k]=0; BQL[n*40+k]=0; }
  __syncthreads();

  // ---- phase A: h1 pre-acts = W1 @ qT (cols >=4 garbage, never stored) ----
  f32x4 aH[4], aX[4];
  #pragma unroll
  for (int i=0;i<4;++i){ aH[i]=(f32x4){0,0,0,0}; aX[i]=(f32x4){0,0,0,0}; }
  {
    const f16x8* WH = (const f16x8*)(ws + OFF_W1H16);
    const f16x8* WL = (const f16x8*)(ws + OFF_W1L16);
    f16x8 Af[4], Al[4];
    #pragma unroll
    for (int i=0;i<4;++i){ int mt=w+4*i; Af[i]=WH[mt*64+l]; Al[i]=WL[mt*64+l]; }
    int off = l15*40 + l4g*8;
    f16x8 Bh = *(const f16x8*)(BQH+off), Bl = *(const f16x8*)(BQL+off);
    #pragma unroll
    for (int i=0;i<4;++i){
      aH[i]=__builtin_amdgcn_mfma_f32_16x16x32_f16(Af[i],Bh,aH[i],0,0,0);
      aX[i]=__builtin_amdgcn_mfma_f32_16x16x32_f16(Af[i],Bl,aX[i],0,0,0);
      aX[i]=__builtin_amdgcn_mfma_f32_16x16x32_f16(Al[i],Bh,aX[i],0,0,0);
    }
  }
  __syncthreads();
  #pragma unroll
  for (int i=0;i<4;++i){
    int m0=(w+4*i)*16+4*l4g;
    float4 bb = *(const float4*)(b1+m0);
    int n = l15;
    if (n < 4){
      unsigned nib=0; unsigned short hs[4], ls[4];
      #pragma unroll
      for (int r=0;r<4;++r){
        float val = aH[i][r] + aX[i][r]*(1.f/4096.f) + ((const float*)&bb)[r];
        if (val > 0.f) nib |= 1u<<r;
        f2h2(leaky(val), &hs[r], &ls[r]);
      }
      mb[n][(m0>>2)] = (unsigned char)nib;
      *(uint2*)(BH2 + n*264 + m0) = make_uint2((unsigned)hs[0]|((unsigned)hs[1]<<16),
                                               (unsigned)hs[2]|((unsigned)hs[3]<<16));
      *(uint2*)(BL2 + n*264 + m0) = make_uint2((unsigned)ls[0]|((unsigned)ls[1]<<16),
                                               (unsigned)ls[2]|((unsigned)ls[3]<<16));
    }
  }
  __syncthreads();
  if (t < 32){ // msk1 -> MSKT
    int n = t&3, w8 = t>>2; unsigned word = 0;
    #pragma unroll
    for (int b=0;b<8;++b) word |= (unsigned)(mb[n][w8*8+b] & 0xFu) << (4*b);
    MSKT[w8*NSAMP + s0+n] = word;
  }

  // ---- phase B: h2 = W2 @ h1 ----
  #pragma unroll
  for (int i=0;i<4;++i){ aH[i]=(f32x4){0,0,0,0}; aX[i]=(f32x4){0,0,0,0}; }
  {
    const f16x8* WH = (const f16x8*)(ws + OFF_W2H16);
    const f16x8* WL = (const f16x8*)(ws + OFF_W2L16);
    for (int kb=0;kb<8;++kb){
      f16x8 Af[4], Al[4];
      #pragma unroll
      for (int i=0;i<4;++i){ int mt=w+4*i; Af[i]=WH[(mt*8+kb)*64+l]; Al[i]=WL[(mt*8+kb)*64+l]; }
      int off = l15*264 + kb*32 + l4g*8;
      f16x8 Bh = *(const f16x8*)(BH2+off), Bl = *(const f16x8*)(BL2+off);
      #pragma unroll
      for (int i=0;i<4;++i){
        aH[i]=__builtin_amdgcn_mfma_f32_16x16x32_f16(Af[i],Bh,aH[i],0,0,0);
        aX[i]=__builtin_amdgcn_mfma_f32_16x16x32_f16(Af[i],Bl,aX[i],0,0,0);
        aX[i]=__builtin_amdgcn_mfma_f32_16x16x32_f16(Al[i],Bh,aX[i],0,0,0);
      }
    }
  }
  __syncthreads();
  #pragma unroll
  for (int i=0;i<4;++i){
    int m0=(w+4*i)*16+4*l4g;
    float4 bb = *(const float4*)(b2+m0);
    int n = l15;
    if (n < 4){
      unsigned nib=0; unsigned short hs[4], ls[4];
      #pragma unroll
      for (int r=0;r<4;++r){
        float val = aH[i][r] + aX[i][r]*(1.f/4096.f) + ((const float*)&bb)[r];
        if (val > 0.f) nib |= 1u<<r;
        f2h2(leaky(val), &hs[r], &ls[r]);
      }
      mb[n][(m0>>2)] = (unsigned char)nib;
      *(uint2*)(BH2 + n*264 + m0) = make_uint2((unsigned)hs[0]|((unsigned)hs[1]<<16),
                                               (unsigned)hs[2]|((unsigned)hs[3]<<16));
      *(uint2*)(BL2 + n*264 + m0) = make_uint2((unsigned)ls[0]|((unsigned)ls[1]<<16),
                                               (unsigned)ls[2]|((unsigned)ls[3]<<16));
    }
  }
  __syncthreads();
  if (t < 32){ // msk2 -> MSKT
    int n = t&3, w8 = t>>2; unsigned word = 0;
    #pragma unroll
    for (int b=0;b<8;++b) word |= (unsigned)(mb[n][w8*8+b] & 0xFu) << (4*b);
    MSKT[(8+w8)*NSAMP + s0+n] = word;
  }

  // ---- phase C: heads = [WLd;WG;WLo;0] @ h2 ----
  for (int pass=0; pass<2; ++pass){
    f32x4 cH[3], cX[3];
    #pragma unroll
    for (int i=0;i<3;++i){ cH[i]=(f32x4){0,0,0,0}; cX[i]=(f32x4){0,0,0,0}; }
    const f16x8* WH = (const f16x8*)(ws + OFF_WHH16);
    const f16x8* WL = (const f16x8*)(ws + OFF_WHL16);
    for (int kb=0;kb<8;++kb){
      f16x8 Af[3], Al[3];
      #pragma unroll
      for (int i=0;i<3;++i){
        int mt = w + 4*(3*pass+i);
        if (mt < 21){ Af[i]=WH[(mt*8+kb)*64+l]; Al[i]=WL[(mt*8+kb)*64+l]; }
      }
      int off = l15*264 + kb*32 + l4g*8;
      f16x8 Bh = *(const f16x8*)(BH2+off), Bl = *(const f16x8*)(BL2+off);
      #pragma unroll
      for (int i=0;i<3;++i){
        int mt = w + 4*(3*pass+i);
        if (mt < 21){
          cH[i]=__builtin_amdgcn_mfma_f32_16x16x32_f16(Af[i],Bh,cH[i],0,0,0);
          cX[i]=__builtin_amdgcn_mfma_f32_16x16x32_f16(Af[i],Bl,cX[i],0,0,0);
          cX[i]=__builtin_amdgcn_mfma_f32_16x16x32_f16(Al[i],Bh,cX[i],0,0,0);
        }
      }
    }
    #pragma unroll
    for (int i=0;i<3;++i){
      int mt = w + 4*(3*pass+i);
      if (mt >= 21) continue;
      int m0 = mt*16+4*l4g;
      int n = l15;
      if (n < 4){
        int sG = s0+n;
        // incremental tri decode for lo tiles (m0 >= 48 -> whole mini-run is lo)
        int tr = 0, tc = 0;
        if (m0 >= 48){
          int p = m0 - 48;
          tr = (int)((1.f + sqrtf(1.f + 8.f*(float)p))*0.5f);
          while (tr*(tr-1)/2 > p) --tr;
          while ((tr+1)*tr/2 <= p) ++tr;
          tc = p - tr*(tr-1)/2;
        }
        #pragma unroll
        for (int r=0;r<4;++r){
          int rr = m0+r;
          float val = cH[i][r] + cX[i][r]*(1.f/4096.f);
          if (rr < 24){
            val += bLd[rr];
            SIGT[rr*NSAMP + sG] = 1.f/(1.f + expf(-val));
            float sp = fmaxf(val,0.f) + log1pf(expf(-fabsf(val)));
            LDT[rr*NSAMP + sG] = sp;
            Lsm[n][rr*25 + rr] = sp;
          } else if (rr < 48){
            out[G_OFF + sG*24 + (rr-24)] = val + bG[rr-24];
          } else if (rr < 324){
            float lov = val + bLo[rr-48];
            LOT[(rr-48)*NSAMP + sG] = lov;
            Lsm[n][tr*25 + tc] = lov;
            if (++tc == tr){ ++tr; tc = 0; }
          }
        }
      }
    }
  }
  __syncthreads();

  // ---- M = L L^T + 1e-9 I (4 samples) ----
  for (int n2 = 0; n2 < 4; ++n2){
    const float* Ls = Lsm[n2];
    for (int e = t; e < 576; e += 256){
      int r = e/24, c = e%24, km = min(r,c);
      float acc = (r == c) ? 1e-9f : 0.f;
      for (int k = 0; k <= km; ++k) acc += Ls[r*25+k]*Ls[c*25+k];
      out[(size_t)(s0+n2)*576 + e] = acc;
    }
  }
  // ---- u[c] = qd[c]*L[c,c] + sum_{r>c} qd[r]*L[r,c] ----
  if (t < 96){
    int n = t/24, c = t%24;
    float u = qd_s[n][c]*Lsm[n][c*25+c];
    for (int r = c+1; r < 24; ++r) u += qd_s[n][r]*Lsm[n][r*25+c];
    UT[c*NSAMP + s0+n] = u;
  }
}

// ---------------- Kernel DE: MFMA Jacobian GEMMs + lean tails (2 samples/block) ----------------
__global__ __launch_bounds__(256, 3) void kDE(
    const float* __restrict__ q_dot, const float* __restrict__ W1g,
    float* __restrict__ ws, float* __restrict__ out)
{
  const int n0 = blockIdx.x*2, t = threadIdx.x;
  const int w = t >> 6, l = t & 63;
  const int l15 = l & 15, l4g = (l >> 4) & 3;
  const unsigned* MSKT = (const unsigned*)(ws + OFF_MSKT);
  const float* SIGT = ws + OFF_SIGT;
  const float* LDT  = ws + OFF_LDT;
  const float* UT   = ws + OFF_UT;
  const float* LOT  = ws + OFF_LOT;

  // pool: [BH|BL] bf16 (50688 B) during GEMMs; tail overlay after
  __shared__ __align__(16) char pool[50688];
  __shared__ unsigned msk[2][16];
  unsigned short* BH = (unsigned short*)pool;
  unsigned short* BL = BH + 12672;
  // tail overlay
  float* dlo_flat = (float*)pool;            // [276*24] flat (faithful view) 26496 B
  float* dld25    = (float*)(pool + 26496);  // [24][25]
  float* qdm_s    = (float*)(pool + 28896);  // [24][25]
  float* um_s     = (float*)(pool + 31296);  // [24][25]
  float* qp2      = (float*)(pool + 33696);  // [1656] dt partials
  float* dtlo     = (float*)(pool + 40320);  // [276]
  float* dtld     = (float*)(pool + 41424);  // [24]
  float* w1s      = (float*)(pool + 41520);  // [24]
  float* sigs     = (float*)(pool + 41616);  // [24]
  float* qds      = (float*)(pool + 41712);  // [24]
  float* uss      = (float*)(pool + 41808);  // [24]
  float* qps      = (float*)(pool + 41904);  // [4][24] quad partials

  if (t < 32) msk[t>>4][t&15] = MSKT[(t&15)*NSAMP + n0 + (t>>4)];
  __syncthreads();

  // ---- Bd = dR1 ⊙ W1 (RNE bf16 split, coalesced W1 row read), thread t owns k=t ----
  {
    float w1r[24];
    #pragma unroll
    for (int d = 0; d < 24; ++d) w1r[d] = W1g[t*24 + d];
    float dr0 = ((msk[0][t>>5] >> (t&31)) & 1u) ? 1.f : -0.01f;
    float dr1 = ((msk[1][t>>5] >> (t&31)) & 1u) ? 1.f : -0.01f;
    #pragma unroll
    for (int c = 0; c < 48; ++c){
      int s = c >= 24, d = c - 24*s;
      float f = (s ? dr1 : dr0) * w1r[d];
      unsigned short h = f2b(f);
      BH[c*264 + t] = h;
      BL[c*264 + t] = f2b(f - b2f(h));
    }
  }
  __syncthreads();

  // ---- Stage D ----
  f32x4 accD[4][3];
  #pragma unroll
  for (int i = 0; i < 4; ++i)
    #pragma unroll
    for (int nt = 0; nt < 3; ++nt) accD[i][nt] = (f32x4){0.f,0.f,0.f,0.f};
  {
    const bf16x8* AHp = (const bf16x8*)(ws + OFF_W2FH);
    const bf16x8* ALp = (const bf16x8*)(ws + OFF_W2FL);
    for (int kb = 0; kb < 8; ++kb){
      bf16x8 AH[4], AL[4], BHf[3], BLf[3];
      #pragma unroll
      for (int i = 0; i < 4; ++i){
        int mt = 4*w + i;
        AH[i] = AHp[(mt*8+kb)*64 + l];
        AL[i] = ALp[(mt*8+kb)*64 + l];
      }
      #pragma unroll
      for (int nt = 0; nt < 3; ++nt){
        int off = (nt*16 + l15)*264 + kb*32 + l4g*8;
        BHf[nt] = *(const bf16x8*)(BH + off);
        BLf[nt] = *(const bf16x8*)(BL + off);
      }
      #pragma unroll
      for (int i = 0; i < 4; ++i)
        #pragma unroll
        for (int nt = 0; nt < 3; ++nt){
          accD[i][nt] = __builtin_amdgcn_mfma_f32_16x16x32_bf16(AH[i], BHf[nt], accD[i][nt], 0, 0, 0);
          accD[i][nt] = __builtin_amdgcn_mfma_f32_16x16x32_bf16(AH[i], BLf[nt], accD[i][nt], 0, 0, 0);
          accD[i][nt] = __builtin_amdgcn_mfma_f32_16x16x32_bf16(AL[i], BHf[nt], accD[i][nt], 0, 0, 0);
        }
    }
  }
  __syncthreads();

  // ---- epilogue D: scale by dR2, truncation split, store J2 over Bd ----
  #pragma unroll
  for (int i = 0; i < 4; ++i){
    int mt = 4*w + i;
    int m0 = mt*16 + 4*l4g;
    int bb = m0 & 31;
    #pragma unroll
    for (int nt = 0; nt < 3; ++nt){
      int c = nt*16 + l15;
      int s = c >= 24;
      unsigned word = msk[s][8 + (mt>>1)];
      unsigned uh[4], ul[4];
      #pragma unroll
      for (int r = 0; r < 4; ++r){
        float sc = ((word >> (bb + r)) & 1u) ? 1.f : -0.01f;
        float v = sc * accD[i][nt][r];
        unsigned uv = __float_as_uint(v);
        uh[r] = uv;
        float lo = v - __uint_as_float(uv & 0xFFFF0000u);
        ul[r] = __float_as_uint(lo);
      }
      *(uint2*)(BH + c*264 + m0) = make_uint2((uh[0]>>16) | (uh[1] & 0xFFFF0000u),
                                              (uh[2]>>16) | (uh[3] & 0xFFFF0000u));
      *(uint2*)(BL + c*264 + m0) = make_uint2((ul[0]>>16) | (ul[1] & 0xFFFF0000u),
                                              (ul[2]>>16) | (ul[3] & 0xFFFF0000u));
    }
  }
  __syncthreads();

  // ---- Stage E ----
  f32x4 accE[5][3];
  #pragma unroll
  for (int i = 0; i < 5; ++i)
    #pragma unroll
    for (int nt = 0; nt < 3; ++nt) accE[i][nt] = (f32x4){0.f,0.f,0.f,0.f};
  {
    const bf16x8* AHp = (const bf16x8*)(ws + OFF_WEFH);
    const bf16x8* ALp = (const bf16x8*)(ws + OFF_WEFL);
    for (int kb = 0; kb < 8; ++kb){
      bf16x8 AH[5], AL[5], BHf[3], BLf[3];
      #pragma unroll
      for (int i = 0; i < 5; ++i){
        int mt = 5*w + i;
        AH[i] = AHp[(mt*8+kb)*64 + l];
        AL[i] = ALp[(mt*8+kb)*64 + l];
      }
      #pragma unroll
      for (int nt = 0; nt < 3; ++nt){
        int off = (nt*16 + l15)*264 + kb*32 + l4g*8;
        BHf[nt] = *(const bf16x8*)(BH + off);
        BLf[nt] = *(const bf16x8*)(BL + off);
      }
      #pragma unroll
      for (int i = 0; i < 5; ++i)
        #pragma unroll
        for (int nt = 0; nt < 3; ++nt){
          accE[i][nt] = __builtin_amdgcn_mfma_f32_16x16x32_bf16(AH[i], BHf[nt], accE[i][nt], 0, 0, 0);
          accE[i][nt] = __builtin_amdgcn_mfma_f32_16x16x32_bf16(AH[i], BLf[nt], accE[i][nt], 0, 0, 0);
          accE[i][nt] = __builtin_amdgcn_mfma_f32_16x16x32_bf16(AL[i], BHf[nt], accE[i][nt], 0, 0, 0);
        }
    }
  }
  __syncthreads();   // pool free for tail overlay

  // ---- lean fused tails, sample-sequential ----
  for (int s = 0; s < 2; ++s){
    const int n = n0 + s;
    // P1: E-scatter + staging
    #pragma unroll
    for (int i = 0; i < 5; ++i){
      int mt = 5*w + i;
      #pragma unroll
      for (int nt = 0; nt < 3; ++nt){
        int c = nt*16 + l15;
        if ((c >= 24) == (s == 1)){
          int d = c - 24*s;
          #pragma unroll
          for (int r = 0; r < 4; ++r){
            int re = mt*16 + 4*l4g + r;
            if (re < 24) dld25[re*25 + d] = accE[i][nt][r];
            else if (re < 300) dlo_flat[(re-24)*24 + d] = accE[i][nt][r];
          }
        }
      }
    }
    for (int e = t; e < 576; e += 256){
      int a_ = e/24, b_ = e%24;
      int ma = (n*24 + a_) & (NSAMP-1);
      int mb_ = (n*24 + b_) & (NSAMP-1);
      qdm_s[a_*25 + b_] = q_dot[ma*24 + b_];
      um_s[a_*25 + b_]  = UT[a_*NSAMP + mb_];
    }
    if (t < 24){
      sigs[t] = SIGT[t*NSAMP + n];
      qds[t]  = q_dot[n*24 + t];
      uss[t]  = UT[t*NSAMP + n];
    }
    __syncthreads();

    // P2: dt partials (sequential b128) + dld_dt
    for (int k = t; k < 1656; k += 256){
      float4 v = *(const float4*)(dlo_flat + 4*k);
      int j4 = (k % 6)*4;
      qp2[k] = v.x*qds[j4] + v.y*qds[j4+1] + v.z*qds[j4+2] + v.w*qds[j4+3];
    }
    if (t < 24){
      float a = 0.f;
      #pragma unroll
      for (int d = 0; d < 24; ++d) a += dld25[t*25+d]*qds[d];
      dtld[t] = sigs[t]*a;
    }
    __syncthreads();

    // P3: dt reduce (grid-stride)
    for (int o = t; o < 276; o += 256){
      float a = 0.f;
      #pragma unroll
      for (int j = 0; j < 6; ++j) a += qp2[o*6+j];
      dtlo[o] = a;
    }
    __syncthreads();

    // P4: quad partials (t<96: 4 stripes x 24 i) || w1 (t in [128,152))
    if (t < 96){
      int g = t/24, i = t%24;
      float part = 0.f;
      for (int c2 = g; c2 < 24; c2 += 4){
        float v = qdm_s[i*25+c2]*sigs[c2]*dld25[c2*25+i];
        for (int r = c2+1; r < 24; ++r){
          int p = r*(r-1)/2 + c2;                 // faithful flat view: f = i*276 + p
          v += qdm_s[i*25+r]*dlo_flat[i*276 + p];
        }
        part += um_s[c2*25+i]*v;
      }
      qps[g*24 + i] = part;
    } else if (t >= 128 && t < 152){
      int i = t - 128;
      float a = qds[i]*dtld[i];
      for (int j = i+1; j < 24; ++j) a += qds[j]*dtlo[j*(j-1)/2 + i];
      w1s[i] = a;
    }
    __syncthreads();

    // P5: c
    if (t < 24){
      const int i = t;
      float cs = dtld[i]*uss[i] + LDT[i*NSAMP + n]*w1s[i];
      for (int k = 0; k < i; ++k){
        int p = i*(i-1)/2 + k;
        cs += LOT[p*NSAMP + n]*w1s[k] + dtlo[p]*uss[k];
      }
      float quad = qps[i] + qps[24+i] + qps[48+i] + qps[72+i];
      out[C_OFF + n*24 + i] = cs - quad;
    }
    __syncthreads();   // before next sample overwrites the overlay
  }
}

extern "C" void kernel_launch(void* const* d_in, const int* in_sizes, int n_in,
                              void* d_out, int out_size, void* d_ws, size_t ws_size,
                              hipStream_t stream)
{
  const float* q   = (const float*)d_in[0];
  const float* qd  = (const float*)d_in[1];
  const float* W1  = (const float*)d_in[2];
  const float* b1  = (const float*)d_in[3];
  const float* W2  = (const float*)d_in[4];
  const float* b2  = (const float*)d_in[5];
  const float* WG  = (const float*)d_in[6];
  const float* bG  = (const float*)d_in[7];
  const float* WLd = (const float*)d_in[8];
  const float* bLd = (const float*)d_in[9];
  const float* WLo = (const float*)d_in[10];
  const float* bLo = (const float*)d_in[11];
  float* out = (float*)d_out;
  float* ws  = (float*)d_ws;

  k0_prep<<<256, 256, 0, stream>>>(W1, W2, WG, WLd, WLo, ws);
  k1_fwd<<<NSAMP/4, 256, 0, stream>>>(q, qd, b1, b2, bG, bLd, bLo, ws, out);
  kDE<<<NSAMP/2, 256, 0, stream>>>(qd, W1, ws, out);
}

// Round 12
// 254.870 us; speedup vs baseline: 1.1039x; 1.1039x over previous
//
#include <hip/hip_runtime.h>
#include <math.h>

#define DIM 24
#define HID 256
#define NLO 276
#define NSAMP 4096
// output layout: M [4096*576] | c [4096*24] | g [4096*24]
#define C_OFF 2359296
#define G_OFF 2457600

// workspace layout (float offsets)
#define OFF_W2FH 0          // bf16 hi, W2 MFMA-A frags (65536 sh)   32768 f
#define OFF_W2FL 32768      // bf16 lo
#define OFF_WEFH 65536      // bf16 hi, [WLd;WLo;0] frags (81920 sh) 40960 f
#define OFF_WEFL 106496
#define OFF_W1H16 147456    // f16 hi, W1 frags (8192 sh)            4096 f
#define OFF_W1L16 151552
#define OFF_W2H16 155648    // f16 hi, W2 frags (65536 sh)           32768 f
#define OFF_W2L16 188416
#define OFF_WHH16 221184    // f16 hi, heads (Ld|G|Lo|0) frags       43008 f
#define OFF_WHL16 264192
// transposed per-sample fields [field][4096]
#define OFF_MSKT 307200     // 16 u32 words x 4096
#define OFF_SIGT 372736     // 24 x 4096
#define OFF_LDT  471040     // 24 x 4096
#define OFF_UT   569344     // 24 x 4096
#define OFF_LOT  667648     // 276 x 4096

typedef __attribute__((ext_vector_type(8))) short bf16x8;
typedef __attribute__((ext_vector_type(8))) _Float16 f16x8;
typedef __attribute__((ext_vector_type(4))) float f32x4;

__device__ __forceinline__ float leaky(float x){ return x > 0.f ? x : 0.01f*x; }
__device__ __forceinline__ unsigned short f2b(float f){           // fp32 -> bf16 RNE
  unsigned u = __float_as_uint(f);
  return (unsigned short)((u + 0x7FFFu + ((u >> 16) & 1u)) >> 16);
}
__device__ __forceinline__ float b2f(unsigned short h){ return __uint_as_float(((unsigned)h) << 16); }
__device__ __forceinline__ void f2h2(float v, unsigned short* hi, unsigned short* lo){
  _Float16 h = (_Float16)v;
  _Float16 l = (_Float16)((v - (float)h) * 4096.f);
  *hi = *(unsigned short*)&h; *lo = *(unsigned short*)&l;
}

// ---------------- Kernel 0: fragment packing ----------------
__global__ __launch_bounds__(256) void k0_prep(
    const float* __restrict__ W1, const float* __restrict__ W2,
    const float* __restrict__ WG, const float* __restrict__ WLd,
    const float* __restrict__ WLo, float* __restrict__ ws)
{
  const int tid = blockIdx.x*256 + threadIdx.x;
  const int nth = gridDim.x*256;
  unsigned short* W2FH = (unsigned short*)(ws + OFF_W2FH);
  unsigned short* W2FL = (unsigned short*)(ws + OFF_W2FL);
  for (int e = tid; e < 65536; e += nth){
    int j=e&7, l=(e>>3)&63, kb=(e>>9)&7, mt=e>>12;
    int m = mt*16+(l&15), k = kb*32+((l>>4)&3)*8+j;
    float v = W2[m*256+k];
    unsigned short h = f2b(v);
    W2FH[e]=h; W2FL[e]=f2b(v-b2f(h));
  }
  unsigned short* WEFH = (unsigned short*)(ws + OFF_WEFH);
  unsigned short* WEFL = (unsigned short*)(ws + OFF_WEFL);
  for (int e = tid; e < 81920; e += nth){
    int j=e&7, l=(e>>3)&63, kb=(e>>9)&7, mt=e>>12;
    int r = mt*16+(l&15), k = kb*32+((l>>4)&3)*8+j;
    float v = 0.f;
    if (r < 24) v = WLd[r*256+k]; else if (r < 300) v = WLo[(r-24)*256+k];
    unsigned short h = f2b(v);
    WEFH[e]=h; WEFL[e]=f2b(v-b2f(h));
  }
  unsigned short* W1H = (unsigned short*)(ws + OFF_W1H16);
  unsigned short* W1L = (unsigned short*)(ws + OFF_W1L16);
  for (int e = tid; e < 8192; e += nth){
    int j=e&7, l=(e>>3)&63, mt=e>>9;
    int m = mt*16+(l&15), k = ((l>>4)&3)*8+j;
    float v = (k < 24) ? W1[m*24+k] : 0.f;
    f2h2(v, &W1H[e], &W1L[e]);
  }
  unsigned short* W2H = (unsigned short*)(ws + OFF_W2H16);
  unsigned short* W2L = (unsigned short*)(ws + OFF_W2L16);
  for (int e = tid; e < 65536; e += nth){
    int j=e&7, l=(e>>3)&63, kb=(e>>9)&7, mt=e>>12;
    int m = mt*16+(l&15), k = kb*32+((l>>4)&3)*8+j;
    f2h2(W2[m*256+k], &W2H[e], &W2L[e]);
  }
  unsigned short* WHH = (unsigned short*)(ws + OFF_WHH16);
  unsigned short* WHL = (unsigned short*)(ws + OFF_WHL16);
  for (int e = tid; e < 86016; e += nth){
    int j=e&7, l=(e>>3)&63, kb=(e>>9)&7, mt=e>>12;
    int rr = mt*16+(l&15), k = kb*32+((l>>4)&3)*8+j;
    float v = 0.f;
    if (rr < 24) v = WLd[rr*256+k];
    else if (rr < 48) v = WG[(rr-24)*256+k];
    else if (rr < 324) v = WLo[(rr-48)*256+k];
    f2h2(v, &WHH[e], &WHL[e]);
  }
}

// ---------------- Kernel 1: MFMA forward + L/M/u (8 samples/block, 512 blocks) ----------------
__global__ __launch_bounds__(256) void k1_fwd(
    const float* __restrict__ q, const float* __restrict__ qd_g,
    const float* __restrict__ b1, const float* __restrict__ b2,
    const float* __restrict__ bG, const float* __restrict__ bLd,
    const float* __restrict__ bLo, float* __restrict__ ws,
    float* __restrict__ out)
{
  const int s0 = blockIdx.x*8, t = threadIdx.x;
  const int w = t>>6, l = t&63, l15 = l&15, l4g = (l>>4)&3;
  unsigned* MSKT = (unsigned*)(ws + OFF_MSKT);
  float* SIGT = ws + OFF_SIGT;
  float* LDT  = ws + OFF_LDT;
  float* UT   = ws + OFF_UT;
  float* LOT  = ws + OFF_LOT;

  __shared__ __align__(16) unsigned short pool[8448];  // BQ (640 sh) -> BH2|BL2 (8448 sh)
  __shared__ unsigned char mb[8][64];
  __shared__ float qd_s[8][24];
  __shared__ float Lsm[8][600];          // per-sample L, stride 25 (diag + strict lower)
  unsigned short* BQH = pool;            // [8][40] f16
  unsigned short* BQL = BQH + 320;
  unsigned short* BH2 = pool;            // [8][264] f16
  unsigned short* BL2 = BH2 + 2112;

  for (int f = t; f < 192; f += 256){
    float v = q[s0*24 + f];
    int n = f/24, k = f%24;
    f2h2(v, &BQH[n*40+k], &BQL[n*40+k]);
    ((float*)qd_s)[f] = qd_g[s0*24 + f];
  }
  if (t < 64){ int n = t>>3, k = 24 + (t&7); BQH[n*40+k]=0; BQL[n*40+k]=0; }
  __syncthreads();

  // ---- phase A: h1 pre-acts = W1 @ qT ----
  f32x4 aH[4], aX[4];
  #pragma unroll
  for (int i=0;i<4;++i){ aH[i]=(f32x4){0,0,0,0}; aX[i]=(f32x4){0,0,0,0}; }
  {
    const f16x8* WH = (const f16x8*)(ws + OFF_W1H16);
    const f16x8* WL = (const f16x8*)(ws + OFF_W1L16);
    f16x8 Af[4], Al[4];
    #pragma unroll
    for (int i=0;i<4;++i){ int mt=w+4*i; Af[i]=WH[mt*64+l]; Al[i]=WL[mt*64+l]; }
    int off = l15*40 + l4g*8;
    f16x8 Bh = *(const f16x8*)(BQH+off), Bl = *(const f16x8*)(BQL+off);
    #pragma unroll
    for (int i=0;i<4;++i){
      aH[i]=__builtin_amdgcn_mfma_f32_16x16x32_f16(Af[i],Bh,aH[i],0,0,0);
      aX[i]=__builtin_amdgcn_mfma_f32_16x16x32_f16(Af[i],Bl,aX[i],0,0,0);
      aX[i]=__builtin_amdgcn_mfma_f32_16x16x32_f16(Al[i],Bh,aX[i],0,0,0);
    }
  }
  __syncthreads();
  #pragma unroll
  for (int i=0;i<4;++i){
    int m0=(w+4*i)*16+4*l4g;
    float4 bb = *(const float4*)(b1+m0);
    int n = l15;
    if (n < 8){
      unsigned nib=0; unsigned short hs[4], ls[4];
      #pragma unroll
      for (int r=0;r<4;++r){
        float val = aH[i][r] + aX[i][r]*(1.f/4096.f) + ((const float*)&bb)[r];
        if (val > 0.f) nib |= 1u<<r;
        f2h2(leaky(val), &hs[r], &ls[r]);
      }
      mb[n][(m0>>2)] = (unsigned char)nib;
      *(uint2*)(BH2 + n*264 + m0) = make_uint2((unsigned)hs[0]|((unsigned)hs[1]<<16),
                                               (unsigned)hs[2]|((unsigned)hs[3]<<16));
      *(uint2*)(BL2 + n*264 + m0) = make_uint2((unsigned)ls[0]|((unsigned)ls[1]<<16),
                                               (unsigned)ls[2]|((unsigned)ls[3]<<16));
    }
  }
  __syncthreads();
  if (t < 64){ // msk1 -> MSKT
    int n = t&7, w8 = t>>3; unsigned word = 0;
    #pragma unroll
    for (int b=0;b<8;++b) word |= (unsigned)(mb[n][w8*8+b] & 0xFu) << (4*b);
    MSKT[w8*NSAMP + s0+n] = word;
  }

  // ---- phase B: h2 = W2 @ h1 ----
  #pragma unroll
  for (int i=0;i<4;++i){ aH[i]=(f32x4){0,0,0,0}; aX[i]=(f32x4){0,0,0,0}; }
  {
    const f16x8* WH = (const f16x8*)(ws + OFF_W2H16);
    const f16x8* WL = (const f16x8*)(ws + OFF_W2L16);
    for (int kb=0;kb<8;++kb){
      f16x8 Af[4], Al[4];
      #pragma unroll
      for (int i=0;i<4;++i){ int mt=w+4*i; Af[i]=WH[(mt*8+kb)*64+l]; Al[i]=WL[(mt*8+kb)*64+l]; }
      int off = l15*264 + kb*32 + l4g*8;
      f16x8 Bh = *(const f16x8*)(BH2+off), Bl = *(const f16x8*)(BL2+off);
      #pragma unroll
      for (int i=0;i<4;++i){
        aH[i]=__builtin_amdgcn_mfma_f32_16x16x32_f16(Af[i],Bh,aH[i],0,0,0);
        aX[i]=__builtin_amdgcn_mfma_f32_16x16x32_f16(Af[i],Bl,aX[i],0,0,0);
        aX[i]=__builtin_amdgcn_mfma_f32_16x16x32_f16(Al[i],Bh,aX[i],0,0,0);
      }
    }
  }
  __syncthreads();
  #pragma unroll
  for (int i=0;i<4;++i){
    int m0=(w+4*i)*16+4*l4g;
    float4 bb = *(const float4*)(b2+m0);
    int n = l15;
    if (n < 8){
      unsigned nib=0; unsigned short hs[4], ls[4];
      #pragma unroll
      for (int r=0;r<4;++r){
        float val = aH[i][r] + aX[i][r]*(1.f/4096.f) + ((const float*)&bb)[r];
        if (val > 0.f) nib |= 1u<<r;
        f2h2(leaky(val), &hs[r], &ls[r]);
      }
      mb[n][(m0>>2)] = (unsigned char)nib;
      *(uint2*)(BH2 + n*264 + m0) = make_uint2((unsigned)hs[0]|((unsigned)hs[1]<<16),
                                               (unsigned)hs[2]|((unsigned)hs[3]<<16));
      *(uint2*)(BL2 + n*264 + m0) = make_uint2((unsigned)ls[0]|((unsigned)ls[1]<<16),
                                               (unsigned)ls[2]|((unsigned)ls[3]<<16));
    }
  }
  __syncthreads();
  if (t < 64){ // msk2 -> MSKT
    int n = t&7, w8 = t>>3; unsigned word = 0;
    #pragma unroll
    for (int b=0;b<8;++b) word |= (unsigned)(mb[n][w8*8+b] & 0xFu) << (4*b);
    MSKT[(8+w8)*NSAMP + s0+n] = word;
  }

  // ---- phase C: heads = [WLd;WG;WLo;0] @ h2 ----
  for (int pass=0; pass<2; ++pass){
    f32x4 cH[3], cX[3];
    #pragma unroll
    for (int i=0;i<3;++i){ cH[i]=(f32x4){0,0,0,0}; cX[i]=(f32x4){0,0,0,0}; }
    const f16x8* WH = (const f16x8*)(ws + OFF_WHH16);
    const f16x8* WL = (const f16x8*)(ws + OFF_WHL16);
    for (int kb=0;kb<8;++kb){
      f16x8 Af[3], Al[3];
      #pragma unroll
      for (int i=0;i<3;++i){
        int mt = w + 4*(3*pass+i);
        if (mt < 21){ Af[i]=WH[(mt*8+kb)*64+l]; Al[i]=WL[(mt*8+kb)*64+l]; }
      }
      int off = l15*264 + kb*32 + l4g*8;
      f16x8 Bh = *(const f16x8*)(BH2+off), Bl = *(const f16x8*)(BL2+off);
      #pragma unroll
      for (int i=0;i<3;++i){
        int mt = w + 4*(3*pass+i);
        if (mt < 21){
          cH[i]=__builtin_amdgcn_mfma_f32_16x16x32_f16(Af[i],Bh,cH[i],0,0,0);
          cX[i]=__builtin_amdgcn_mfma_f32_16x16x32_f16(Af[i],Bl,cX[i],0,0,0);
          cX[i]=__builtin_amdgcn_mfma_f32_16x16x32_f16(Al[i],Bh,cX[i],0,0,0);
        }
      }
    }
    #pragma unroll
    for (int i=0;i<3;++i){
      int mt = w + 4*(3*pass+i);
      if (mt >= 21) continue;
      int m0 = mt*16+4*l4g;
      int n = l15;
      if (n < 8){
        int sG = s0+n;
        // incremental tri decode for lo tiles (m0 >= 48 -> whole mini-run is lo)
        int tr = 0, tc = 0;
        if (m0 >= 48){
          int p = m0 - 48;
          tr = (int)((1.f + sqrtf(1.f + 8.f*(float)p))*0.5f);
          while (tr*(tr-1)/2 > p) --tr;
          while ((tr+1)*tr/2 <= p) ++tr;
          tc = p - tr*(tr-1)/2;
        }
        #pragma unroll
        for (int r=0;r<4;++r){
          int rr = m0+r;
          float val = cH[i][r] + cX[i][r]*(1.f/4096.f);
          if (rr < 24){
            val += bLd[rr];
            SIGT[rr*NSAMP + sG] = 1.f/(1.f + expf(-val));
            float sp = fmaxf(val,0.f) + log1pf(expf(-fabsf(val)));
            LDT[rr*NSAMP + sG] = sp;
            Lsm[n][rr*25 + rr] = sp;
          } else if (rr < 48){
            out[G_OFF + sG*24 + (rr-24)] = val + bG[rr-24];
          } else if (rr < 324){
            float lov = val + bLo[rr-48];
            LOT[(rr-48)*NSAMP + sG] = lov;
            Lsm[n][tr*25 + tc] = lov;
            if (++tc == tr){ ++tr; tc = 0; }
          }
        }
      }
    }
  }
  __syncthreads();

  // ---- M = L L^T + 1e-9 I (8 samples) ----
  for (int n2 = 0; n2 < 8; ++n2){
    const float* Ls = Lsm[n2];
    for (int e = t; e < 576; e += 256){
      int r = e/24, c = e%24, km = min(r,c);
      float acc = (r == c) ? 1e-9f : 0.f;
      for (int k = 0; k <= km; ++k) acc += Ls[r*25+k]*Ls[c*25+k];
      out[(size_t)(s0+n2)*576 + e] = acc;
    }
  }
  // ---- u[c] = qd[c]*L[c,c] + sum_{r>c} qd[r]*L[r,c] ----
  if (t < 192){
    int n = t/24, c = t%24;
    float u = qd_s[n][c]*Lsm[n][c*25+c];
    for (int r = c+1; r < 24; ++r) u += qd_s[n][r]*Lsm[n][r*25+c];
    UT[c*NSAMP + s0+n] = u;
  }
}

// ---------------- Kernel DE: MFMA Jacobian GEMMs + lean tails (2 samples/block) ----------------
__global__ __launch_bounds__(256, 3) void kDE(
    const float* __restrict__ q_dot, const float* __restrict__ W1g,
    float* __restrict__ ws, float* __restrict__ out)
{
  const int n0 = blockIdx.x*2, t = threadIdx.x;
  const int w = t >> 6, l = t & 63;
  const int l15 = l & 15, l4g = (l >> 4) & 3;
  const unsigned* MSKT = (const unsigned*)(ws + OFF_MSKT);
  const float* SIGT = ws + OFF_SIGT;
  const float* LDT  = ws + OFF_LDT;
  const float* UT   = ws + OFF_UT;
  const float* LOT  = ws + OFF_LOT;

  // pool: [BH|BL] bf16 (50688 B) during GEMMs; tail overlay after
  __shared__ __align__(16) char pool[50688];
  __shared__ unsigned msk[2][16];
  unsigned short* BH = (unsigned short*)pool;
  unsigned short* BL = BH + 12672;
  // tail overlay
  float* dlo_flat = (float*)pool;            // [276*24] flat (faithful view) 26496 B
  float* dld25    = (float*)(pool + 26496);  // [24][25]
  float* qdm_s    = (float*)(pool + 28896);  // [24][25]
  float* um_s     = (float*)(pool + 31296);  // [24][25]
  float* qp2      = (float*)(pool + 33696);  // [1656] dt partials
  float* dtlo     = (float*)(pool + 40320);  // [276]
  float* dtld     = (float*)(pool + 41424);  // [24]
  float* w1s      = (float*)(pool + 41520);  // [24]
  float* sigs     = (float*)(pool + 41616);  // [24]
  float* qds      = (float*)(pool + 41712);  // [24]
  float* uss      = (float*)(pool + 41808);  // [24]
  float* qps      = (float*)(pool + 41904);  // [4][24] quad partials

  if (t < 32) msk[t>>4][t&15] = MSKT[(t&15)*NSAMP + n0 + (t>>4)];
  __syncthreads();

  // ---- Bd = dR1 ⊙ W1 (RNE bf16 split, coalesced W1 row read), thread t owns k=t ----
  {
    float w1r[24];
    #pragma unroll
    for (int d = 0; d < 24; ++d) w1r[d] = W1g[t*24 + d];
    float dr0 = ((msk[0][t>>5] >> (t&31)) & 1u) ? 1.f : -0.01f;
    float dr1 = ((msk[1][t>>5] >> (t&31)) & 1u) ? 1.f : -0.01f;
    #pragma unroll
    for (int c = 0; c < 48; ++c){
      int s = c >= 24, d = c - 24*s;
      float f = (s ? dr1 : dr0) * w1r[d];
      unsigned short h = f2b(f);
      BH[c*264 + t] = h;
      BL[c*264 + t] = f2b(f - b2f(h));
    }
  }
  __syncthreads();

  // ---- Stage D ----
  f32x4 accD[4][3];
  #pragma unroll
  for (int i = 0; i < 4; ++i)
    #pragma unroll
    for (int nt = 0; nt < 3; ++nt) accD[i][nt] = (f32x4){0.f,0.f,0.f,0.f};
  {
    const bf16x8* AHp = (const bf16x8*)(ws + OFF_W2FH);
    const bf16x8* ALp = (const bf16x8*)(ws + OFF_W2FL);
    for (int kb = 0; kb < 8; ++kb){
      bf16x8 AH[4], AL[4], BHf[3], BLf[3];
      #pragma unroll
      for (int i = 0; i < 4; ++i){
        int mt = 4*w + i;
        AH[i] = AHp[(mt*8+kb)*64 + l];
        AL[i] = ALp[(mt*8+kb)*64 + l];
      }
      #pragma unroll
      for (int nt = 0; nt < 3; ++nt){
        int off = (nt*16 + l15)*264 + kb*32 + l4g*8;
        BHf[nt] = *(const bf16x8*)(BH + off);
        BLf[nt] = *(const bf16x8*)(BL + off);
      }
      #pragma unroll
      for (int i = 0; i < 4; ++i)
        #pragma unroll
        for (int nt = 0; nt < 3; ++nt){
          accD[i][nt] = __builtin_amdgcn_mfma_f32_16x16x32_bf16(AH[i], BHf[nt], accD[i][nt], 0, 0, 0);
          accD[i][nt] = __builtin_amdgcn_mfma_f32_16x16x32_bf16(AH[i], BLf[nt], accD[i][nt], 0, 0, 0);
          accD[i][nt] = __builtin_amdgcn_mfma_f32_16x16x32_bf16(AL[i], BHf[nt], accD[i][nt], 0, 0, 0);
        }
    }
  }
  __syncthreads();

  // ---- epilogue D: scale by dR2, truncation split, store J2 over Bd ----
  #pragma unroll
  for (int i = 0; i < 4; ++i){
    int mt = 4*w + i;
    int m0 = mt*16 + 4*l4g;
    int bb = m0 & 31;
    #pragma unroll
    for (int nt = 0; nt < 3; ++nt){
      int c = nt*16 + l15;
      int s = c >= 24;
      unsigned word = msk[s][8 + (mt>>1)];
      unsigned uh[4], ul[4];
      #pragma unroll
      for (int r = 0; r < 4; ++r){
        float sc = ((word >> (bb + r)) & 1u) ? 1.f : -0.01f;
        float v = sc * accD[i][nt][r];
        unsigned uv = __float_as_uint(v);
        uh[r] = uv;
        float lo = v - __uint_as_float(uv & 0xFFFF0000u);
        ul[r] = __float_as_uint(lo);
      }
      *(uint2*)(BH + c*264 + m0) = make_uint2((uh[0]>>16) | (uh[1] & 0xFFFF0000u),
                                              (uh[2]>>16) | (uh[3] & 0xFFFF0000u));
      *(uint2*)(BL + c*264 + m0) = make_uint2((ul[0]>>16) | (ul[1] & 0xFFFF0000u),
                                              (ul[2]>>16) | (ul[3] & 0xFFFF0000u));
    }
  }
  __syncthreads();

  // ---- Stage E ----
  f32x4 accE[5][3];
  #pragma unroll
  for (int i = 0; i < 5; ++i)
    #pragma unroll
    for (int nt = 0; nt < 3; ++nt) accE[i][nt] = (f32x4){0.f,0.f,0.f,0.f};
  {
    const bf16x8* AHp = (const bf16x8*)(ws + OFF_WEFH);
    const bf16x8* ALp = (const bf16x8*)(ws + OFF_WEFL);
    for (int kb = 0; kb < 8; ++kb){
      bf16x8 AH[5], AL[5], BHf[3], BLf[3];
      #pragma unroll
      for (int i = 0; i < 5; ++i){
        int mt = 5*w + i;
        AH[i] = AHp[(mt*8+kb)*64 + l];
        AL[i] = ALp[(mt*8+kb)*64 + l];
      }
      #pragma unroll
      for (int nt = 0; nt < 3; ++nt){
        int off = (nt*16 + l15)*264 + kb*32 + l4g*8;
        BHf[nt] = *(const bf16x8*)(BH + off);
        BLf[nt] = *(const bf16x8*)(BL + off);
      }
      #pragma unroll
      for (int i = 0; i < 5; ++i)
        #pragma unroll
        for (int nt = 0; nt < 3; ++nt){
          accE[i][nt] = __builtin_amdgcn_mfma_f32_16x16x32_bf16(AH[i], BHf[nt], accE[i][nt], 0, 0, 0);
          accE[i][nt] = __builtin_amdgcn_mfma_f32_16x16x32_bf16(AH[i], BLf[nt], accE[i][nt], 0, 0, 0);
          accE[i][nt] = __builtin_amdgcn_mfma_f32_16x16x32_bf16(AL[i], BHf[nt], accE[i][nt], 0, 0, 0);
        }
    }
  }
  __syncthreads();   // pool free for tail overlay

  // ---- lean fused tails, sample-sequential ----
  for (int s = 0; s < 2; ++s){
    const int n = n0 + s;
    // P1: E-scatter + staging
    #pragma unroll
    for (int i = 0; i < 5; ++i){
      int mt = 5*w + i;
      #pragma unroll
      for (int nt = 0; nt < 3; ++nt){
        int c = nt*16 + l15;
        if ((c >= 24) == (s == 1)){
          int d = c - 24*s;
          #pragma unroll
          for (int r = 0; r < 4; ++r){
            int re = mt*16 + 4*l4g + r;
            if (re < 24) dld25[re*25 + d] = accE[i][nt][r];
            else if (re < 300) dlo_flat[(re-24)*24 + d] = accE[i][nt][r];
          }
        }
      }
    }
    for (int e = t; e < 576; e += 256){
      int a_ = e/24, b_ = e%24;
      int ma = (n*24 + a_) & (NSAMP-1);
      int mb_ = (n*24 + b_) & (NSAMP-1);
      qdm_s[a_*25 + b_] = q_dot[ma*24 + b_];
      um_s[a_*25 + b_]  = UT[a_*NSAMP + mb_];
    }
    if (t < 24){
      sigs[t] = SIGT[t*NSAMP + n];
      qds[t]  = q_dot[n*24 + t];
      uss[t]  = UT[t*NSAMP + n];
    }
    __syncthreads();

    // P2: dt partials (sequential b128) + dld_dt
    for (int k = t; k < 1656; k += 256){
      float4 v = *(const float4*)(dlo_flat + 4*k);
      int j4 = (k % 6)*4;
      qp2[k] = v.x*qds[j4] + v.y*qds[j4+1] + v.z*qds[j4+2] + v.w*qds[j4+3];
    }
    if (t < 24){
      float a = 0.f;
      #pragma unroll
      for (int d = 0; d < 24; ++d) a += dld25[t*25+d]*qds[d];
      dtld[t] = sigs[t]*a;
    }
    __syncthreads();

    // P3: dt reduce (grid-stride)
    for (int o = t; o < 276; o += 256){
      float a = 0.f;
      #pragma unroll
      for (int j = 0; j < 6; ++j) a += qp2[o*6+j];
      dtlo[o] = a;
    }
    __syncthreads();

    // P4: quad partials (t<96: 4 stripes x 24 i) || w1 (t in [128,152))
    if (t < 96){
      int g = t/24, i = t%24;
      float part = 0.f;
      for (int c2 = g; c2 < 24; c2 += 4){
        float v = qdm_s[i*25+c2]*sigs[c2]*dld25[c2*25+i];
        for (int r = c2+1; r < 24; ++r){
          int p = r*(r-1)/2 + c2;                 // faithful flat view: f = i*276 + p
          v += qdm_s[i*25+r]*dlo_flat[i*276 + p];
        }
        part += um_s[c2*25+i]*v;
      }
      qps[g*24 + i] = part;
    } else if (t >= 128 && t < 152){
      int i = t - 128;
      float a = qds[i]*dtld[i];
      for (int j = i+1; j < 24; ++j) a += qds[j]*dtlo[j*(j-1)/2 + i];
      w1s[i] = a;
    }
    __syncthreads();

    // P5: c
    if (t < 24){
      const int i = t;
      float cs = dtld[i]*uss[i] + LDT[i*NSAMP + n]*w1s[i];
      for (int k = 0; k < i; ++k){
        int p = i*(i-1)/2 + k;
        cs += LOT[p*NSAMP + n]*w1s[k] + dtlo[p]*uss[k];
      }
      float quad = qps[i] + qps[24+i] + qps[48+i] + qps[72+i];
      out[C_OFF + n*24 + i] = cs - quad;
    }
    __syncthreads();   // before next sample overwrites the overlay
  }
}

extern "C" void kernel_launch(void* const* d_in, const int* in_sizes, int n_in,
                              void* d_out, int out_size, void* d_ws, size_t ws_size,
                              hipStream_t stream)
{
  const float* q   = (const float*)d_in[0];
  const float* qd  = (const float*)d_in[1];
  const float* W1  = (const float*)d_in[2];
  const float* b1  = (const float*)d_in[3];
  const float* W2  = (const float*)d_in[4];
  const float* b2  = (const float*)d_in[5];
  const float* WG  = (const float*)d_in[6];
  const float* bG  = (const float*)d_in[7];
  const float* WLd = (const float*)d_in[8];
  const float* bLd = (const float*)d_in[9];
  const float* WLo = (const float*)d_in[10];
  const float* bLo = (const float*)d_in[11];
  float* out = (float*)d_out;
  float* ws  = (float*)d_ws;

  k0_prep<<<256, 256, 0, stream>>>(W1, W2, WG, WLd, WLo, ws);
  k1_fwd<<<NSAMP/8, 256, 0, stream>>>(q, qd, b1, b2, bG, bLd, bLo, ws, out);
  kDE<<<NSAMP/2, 256, 0, stream>>>(qd, W1, ws, out);
}

// Round 13
// 243.656 us; speedup vs baseline: 1.1547x; 1.0460x over previous
//
#include <hip/hip_runtime.h>
#include <math.h>

#define DIM 24
#define HID 256
#define NLO 276
#define NSAMP 4096
// output layout: M [4096*576] | c [4096*24] | g [4096*24]
#define C_OFF 2359296
#define G_OFF 2457600

// workspace layout (float offsets)
#define OFF_W2FH 0          // bf16 hi, W2 MFMA-A frags (65536 sh)   32768 f
#define OFF_W2FL 32768      // bf16 lo
#define OFF_WEFH 65536      // bf16 hi, [WLd;WLo;0] frags (81920 sh) 40960 f
#define OFF_WEFL 106496
#define OFF_W1H16 147456    // f16 hi, W1 frags (8192 sh)            4096 f
#define OFF_W1L16 151552
#define OFF_W2H16 155648    // f16 hi, W2 frags (65536 sh)           32768 f
#define OFF_W2L16 188416
#define OFF_WHH16 221184    // f16 hi, heads (Ld|G|Lo|0) frags       43008 f
#define OFF_WHL16 264192
// transposed per-sample fields [field][4096]
#define OFF_MSKT 307200     // 16 u32 words x 4096
#define OFF_SIGT 372736     // 24 x 4096
#define OFF_LDT  471040     // 24 x 4096
#define OFF_UT   569344     // 24 x 4096
#define OFF_LOT  667648     // 276 x 4096

typedef __attribute__((ext_vector_type(8))) short bf16x8;
typedef __attribute__((ext_vector_type(8))) _Float16 f16x8;
typedef __attribute__((ext_vector_type(4))) float f32x4;

__device__ __forceinline__ float leaky(float x){ return x > 0.f ? x : 0.01f*x; }
__device__ __forceinline__ unsigned short f2b(float f){           // fp32 -> bf16 RNE
  unsigned u = __float_as_uint(f);
  return (unsigned short)((u + 0x7FFFu + ((u >> 16) & 1u)) >> 16);
}
__device__ __forceinline__ float b2f(unsigned short h){ return __uint_as_float(((unsigned)h) << 16); }
__device__ __forceinline__ void f2h2(float v, unsigned short* hi, unsigned short* lo){
  _Float16 h = (_Float16)v;
  _Float16 l = (_Float16)((v - (float)h) * 4096.f);
  *hi = *(unsigned short*)&h; *lo = *(unsigned short*)&l;
}

// ---------------- Kernel 0: fragment packing ----------------
__global__ __launch_bounds__(256) void k0_prep(
    const float* __restrict__ W1, const float* __restrict__ W2,
    const float* __restrict__ WG, const float* __restrict__ WLd,
    const float* __restrict__ WLo, float* __restrict__ ws)
{
  const int tid = blockIdx.x*256 + threadIdx.x;
  const int nth = gridDim.x*256;
  unsigned short* W2FH = (unsigned short*)(ws + OFF_W2FH);
  unsigned short* W2FL = (unsigned short*)(ws + OFF_W2FL);
  for (int e = tid; e < 65536; e += nth){
    int j=e&7, l=(e>>3)&63, kb=(e>>9)&7, mt=e>>12;
    int m = mt*16+(l&15), k = kb*32+((l>>4)&3)*8+j;
    float v = W2[m*256+k];
    unsigned short h = f2b(v);
    W2FH[e]=h; W2FL[e]=f2b(v-b2f(h));
  }
  unsigned short* WEFH = (unsigned short*)(ws + OFF_WEFH);
  unsigned short* WEFL = (unsigned short*)(ws + OFF_WEFL);
  for (int e = tid; e < 81920; e += nth){
    int j=e&7, l=(e>>3)&63, kb=(e>>9)&7, mt=e>>12;
    int r = mt*16+(l&15), k = kb*32+((l>>4)&3)*8+j;
    float v = 0.f;
    if (r < 24) v = WLd[r*256+k]; else if (r < 300) v = WLo[(r-24)*256+k];
    unsigned short h = f2b(v);
    WEFH[e]=h; WEFL[e]=f2b(v-b2f(h));
  }
  unsigned short* W1H = (unsigned short*)(ws + OFF_W1H16);
  unsigned short* W1L = (unsigned short*)(ws + OFF_W1L16);
  for (int e = tid; e < 8192; e += nth){
    int j=e&7, l=(e>>3)&63, mt=e>>9;
    int m = mt*16+(l&15), k = ((l>>4)&3)*8+j;
    float v = (k < 24) ? W1[m*24+k] : 0.f;
    f2h2(v, &W1H[e], &W1L[e]);
  }
  unsigned short* W2H = (unsigned short*)(ws + OFF_W2H16);
  unsigned short* W2L = (unsigned short*)(ws + OFF_W2L16);
  for (int e = tid; e < 65536; e += nth){
    int j=e&7, l=(e>>3)&63, kb=(e>>9)&7, mt=e>>12;
    int m = mt*16+(l&15), k = kb*32+((l>>4)&3)*8+j;
    f2h2(W2[m*256+k], &W2H[e], &W2L[e]);
  }
  unsigned short* WHH = (unsigned short*)(ws + OFF_WHH16);
  unsigned short* WHL = (unsigned short*)(ws + OFF_WHL16);
  for (int e = tid; e < 86016; e += nth){
    int j=e&7, l=(e>>3)&63, kb=(e>>9)&7, mt=e>>12;
    int rr = mt*16+(l&15), k = kb*32+((l>>4)&3)*8+j;
    float v = 0.f;
    if (rr < 24) v = WLd[rr*256+k];
    else if (rr < 48) v = WG[(rr-24)*256+k];
    else if (rr < 324) v = WLo[(rr-48)*256+k];
    f2h2(v, &WHH[e], &WHL[e]);
  }
}

// ---------------- Kernel 1: MFMA forward + L/M/u (16 samples/block, 256 blocks, 512 thr) ----------------
__global__ __launch_bounds__(512) void k1_fwd(
    const float* __restrict__ q, const float* __restrict__ qd_g,
    const float* __restrict__ b1, const float* __restrict__ b2,
    const float* __restrict__ bG, const float* __restrict__ bLd,
    const float* __restrict__ bLo, float* __restrict__ ws,
    float* __restrict__ out)
{
  const int s0 = blockIdx.x*16, t = threadIdx.x;
  const int w = t>>6, l = t&63, l15 = l&15, l4g = (l>>4)&3;
  unsigned* MSKT = (unsigned*)(ws + OFF_MSKT);
  float* SIGT = ws + OFF_SIGT;
  float* LDT  = ws + OFF_LDT;
  float* UT   = ws + OFF_UT;
  float* LOT  = ws + OFF_LOT;

  __shared__ __align__(16) unsigned short pool[8448];  // BQ (1280 sh) -> BH2|BL2 (8448 sh)
  __shared__ unsigned char mb[16][64];
  __shared__ float qd_s[16][24];
  __shared__ float Lsm[16][600];         // per-sample L, stride 25
  unsigned short* BQH = pool;            // [16][40] f16
  unsigned short* BQL = BQH + 640;
  unsigned short* BH2 = pool;            // [16][264] f16
  unsigned short* BL2 = BH2 + 4224;

  if (t < 384){
    float v = q[s0*24 + t];
    int n = t/24, k = t%24;
    f2h2(v, &BQH[n*40+k], &BQL[n*40+k]);
    ((float*)qd_s)[t] = qd_g[s0*24 + t];
  }
  if (t < 256){ int n = t>>4, k = 24 + (t&15); BQH[n*40+k]=0; BQL[n*40+k]=0; }
  __syncthreads();

  // ---- phase A: h1 pre-acts = W1 @ qT (all 16 N-cols valid) ----
  f32x4 aH[2], aX[2];
  #pragma unroll
  for (int i=0;i<2;++i){ aH[i]=(f32x4){0,0,0,0}; aX[i]=(f32x4){0,0,0,0}; }
  {
    const f16x8* WH = (const f16x8*)(ws + OFF_W1H16);
    const f16x8* WL = (const f16x8*)(ws + OFF_W1L16);
    f16x8 Af[2], Al[2];
    #pragma unroll
    for (int i=0;i<2;++i){ int mt=w+8*i; Af[i]=WH[mt*64+l]; Al[i]=WL[mt*64+l]; }
    int off = l15*40 + l4g*8;
    f16x8 Bh = *(const f16x8*)(BQH+off), Bl = *(const f16x8*)(BQL+off);
    #pragma unroll
    for (int i=0;i<2;++i){
      aH[i]=__builtin_amdgcn_mfma_f32_16x16x32_f16(Af[i],Bh,aH[i],0,0,0);
      aX[i]=__builtin_amdgcn_mfma_f32_16x16x32_f16(Af[i],Bl,aX[i],0,0,0);
      aX[i]=__builtin_amdgcn_mfma_f32_16x16x32_f16(Al[i],Bh,aX[i],0,0,0);
    }
  }
  __syncthreads();
  #pragma unroll
  for (int i=0;i<2;++i){
    int m0=(w+8*i)*16+4*l4g;
    float4 bb = *(const float4*)(b1+m0);
    int n = l15;
    unsigned nib=0; unsigned short hs[4], ls[4];
    #pragma unroll
    for (int r=0;r<4;++r){
      float val = aH[i][r] + aX[i][r]*(1.f/4096.f) + ((const float*)&bb)[r];
      if (val > 0.f) nib |= 1u<<r;
      f2h2(leaky(val), &hs[r], &ls[r]);
    }
    mb[n][(m0>>2)] = (unsigned char)nib;
    *(uint2*)(BH2 + n*264 + m0) = make_uint2((unsigned)hs[0]|((unsigned)hs[1]<<16),
                                             (unsigned)hs[2]|((unsigned)hs[3]<<16));
    *(uint2*)(BL2 + n*264 + m0) = make_uint2((unsigned)ls[0]|((unsigned)ls[1]<<16),
                                             (unsigned)ls[2]|((unsigned)ls[3]<<16));
  }
  __syncthreads();
  if (t < 128){ // msk1 -> MSKT
    int n = t&15, w8 = t>>4; unsigned word = 0;
    #pragma unroll
    for (int b=0;b<8;++b) word |= (unsigned)(mb[n][w8*8+b] & 0xFu) << (4*b);
    MSKT[w8*NSAMP + s0+n] = word;
  }

  // ---- phase B: h2 = W2 @ h1 ----
  #pragma unroll
  for (int i=0;i<2;++i){ aH[i]=(f32x4){0,0,0,0}; aX[i]=(f32x4){0,0,0,0}; }
  {
    const f16x8* WH = (const f16x8*)(ws + OFF_W2H16);
    const f16x8* WL = (const f16x8*)(ws + OFF_W2L16);
    for (int kb=0;kb<8;++kb){
      f16x8 Af[2], Al[2];
      #pragma unroll
      for (int i=0;i<2;++i){ int mt=w+8*i; Af[i]=WH[(mt*8+kb)*64+l]; Al[i]=WL[(mt*8+kb)*64+l]; }
      int off = l15*264 + kb*32 + l4g*8;
      f16x8 Bh = *(const f16x8*)(BH2+off), Bl = *(const f16x8*)(BL2+off);
      #pragma unroll
      for (int i=0;i<2;++i){
        aH[i]=__builtin_amdgcn_mfma_f32_16x16x32_f16(Af[i],Bh,aH[i],0,0,0);
        aX[i]=__builtin_amdgcn_mfma_f32_16x16x32_f16(Af[i],Bl,aX[i],0,0,0);
        aX[i]=__builtin_amdgcn_mfma_f32_16x16x32_f16(Al[i],Bh,aX[i],0,0,0);
      }
    }
  }
  __syncthreads();
  #pragma unroll
  for (int i=0;i<2;++i){
    int m0=(w+8*i)*16+4*l4g;
    float4 bb = *(const float4*)(b2+m0);
    int n = l15;
    unsigned nib=0; unsigned short hs[4], ls[4];
    #pragma unroll
    for (int r=0;r<4;++r){
      float val = aH[i][r] + aX[i][r]*(1.f/4096.f) + ((const float*)&bb)[r];
      if (val > 0.f) nib |= 1u<<r;
      f2h2(leaky(val), &hs[r], &ls[r]);
    }
    mb[n][(m0>>2)] = (unsigned char)nib;
    *(uint2*)(BH2 + n*264 + m0) = make_uint2((unsigned)hs[0]|((unsigned)hs[1]<<16),
                                             (unsigned)hs[2]|((unsigned)hs[3]<<16));
    *(uint2*)(BL2 + n*264 + m0) = make_uint2((unsigned)ls[0]|((unsigned)ls[1]<<16),
                                             (unsigned)ls[2]|((unsigned)ls[3]<<16));
  }
  __syncthreads();
  if (t < 128){ // msk2 -> MSKT
    int n = t&15, w8 = t>>4; unsigned word = 0;
    #pragma unroll
    for (int b=0;b<8;++b) word |= (unsigned)(mb[n][w8*8+b] & 0xFu) << (4*b);
    MSKT[(8+w8)*NSAMP + s0+n] = word;
  }

  // ---- phase C: heads = [WLd;WG;WLo;0] @ h2 (21 M-tiles over 8 waves x 3 passes) ----
  for (int pass=0; pass<3; ++pass){
    int mt = w + 8*pass;
    bool act = (mt < 21);
    f32x4 cH=(f32x4){0,0,0,0}, cX=(f32x4){0,0,0,0};
    const f16x8* WH = (const f16x8*)(ws + OFF_WHH16);
    const f16x8* WL = (const f16x8*)(ws + OFF_WHL16);
    for (int kb=0;kb<8;++kb){
      f16x8 Af, Al;
      if (act){ Af=WH[(mt*8+kb)*64+l]; Al=WL[(mt*8+kb)*64+l]; }
      int off = l15*264 + kb*32 + l4g*8;
      f16x8 Bh = *(const f16x8*)(BH2+off), Bl = *(const f16x8*)(BL2+off);
      if (act){
        cH=__builtin_amdgcn_mfma_f32_16x16x32_f16(Af,Bh,cH,0,0,0);
        cX=__builtin_amdgcn_mfma_f32_16x16x32_f16(Af,Bl,cX,0,0,0);
        cX=__builtin_amdgcn_mfma_f32_16x16x32_f16(Al,Bh,cX,0,0,0);
      }
    }
    if (act){
      int m0 = mt*16+4*l4g;
      int n = l15, sG = s0+n;
      // incremental tri decode for lo tiles (runs of 4 never straddle 24/48)
      int tr = 0, tc = 0;
      if (m0 >= 48){
        int p = m0 - 48;
        tr = (int)((1.f + sqrtf(1.f + 8.f*(float)p))*0.5f);
        while (tr*(tr-1)/2 > p) --tr;
        while ((tr+1)*tr/2 <= p) ++tr;
        tc = p - tr*(tr-1)/2;
      }
      #pragma unroll
      for (int r=0;r<4;++r){
        int rr = m0+r;
        float val = cH[r] + cX[r]*(1.f/4096.f);
        if (rr < 24){
          val += bLd[rr];
          SIGT[rr*NSAMP + sG] = 1.f/(1.f + expf(-val));
          float sp = fmaxf(val,0.f) + log1pf(expf(-fabsf(val)));
          LDT[rr*NSAMP + sG] = sp;
          Lsm[n][rr*25 + rr] = sp;
        } else if (rr < 48){
          out[G_OFF + sG*24 + (rr-24)] = val + bG[rr-24];
        } else if (rr < 324){
          float lov = val + bLo[rr-48];
          LOT[(rr-48)*NSAMP + sG] = lov;
          Lsm[n][tr*25 + tc] = lov;
          if (++tc == tr){ ++tr; tc = 0; }
        }
      }
    }
  }
  __syncthreads();

  // ---- M = L L^T + 1e-9 I (16 samples) ----
  for (int n2 = 0; n2 < 16; ++n2){
    const float* Ls = Lsm[n2];
    for (int e = t; e < 576; e += 512){
      int r = e/24, c = e%24, km = min(r,c);
      float acc = (r == c) ? 1e-9f : 0.f;
      for (int k = 0; k <= km; ++k) acc += Ls[r*25+k]*Ls[c*25+k];
      out[(size_t)(s0+n2)*576 + e] = acc;
    }
  }
  // ---- u[c] = qd[c]*L[c,c] + sum_{r>c} qd[r]*L[r,c] ----
  if (t < 384){
    int n = t/24, c = t%24;
    float u = qd_s[n][c]*Lsm[n][c*25+c];
    for (int r = c+1; r < 24; ++r) u += qd_s[n][r]*Lsm[n][r*25+c];
    UT[c*NSAMP + s0+n] = u;
  }
}

// ---------------- Kernel DE: MFMA Jacobian GEMMs + lean tails (2 samples/block) ----------------
__global__ __launch_bounds__(256, 3) void kDE(
    const float* __restrict__ q_dot, const float* __restrict__ W1g,
    float* __restrict__ ws, float* __restrict__ out)
{
  const int n0 = blockIdx.x*2, t = threadIdx.x;
  const int w = t >> 6, l = t & 63;
  const int l15 = l & 15, l4g = (l >> 4) & 3;
  const unsigned* MSKT = (const unsigned*)(ws + OFF_MSKT);
  const float* SIGT = ws + OFF_SIGT;
  const float* LDT  = ws + OFF_LDT;
  const float* UT   = ws + OFF_UT;
  const float* LOT  = ws + OFF_LOT;

  // pool: [BH|BL] bf16 (50688 B) during GEMMs; tail overlay after
  __shared__ __align__(16) char pool[50688];
  __shared__ unsigned msk[2][16];
  unsigned short* BH = (unsigned short*)pool;
  unsigned short* BL = BH + 12672;
  // tail overlay
  float* dlo_flat = (float*)pool;            // [276*24] flat (faithful view) 26496 B
  float* dld25    = (float*)(pool + 26496);  // [24][25]
  float* qdm_s    = (float*)(pool + 28896);  // [24][25]
  float* um_s     = (float*)(pool + 31296);  // [24][25]
  float* qp2      = (float*)(pool + 33696);  // [1656] dt partials
  float* dtlo     = (float*)(pool + 40320);  // [276]
  float* dtld     = (float*)(pool + 41424);  // [24]
  float* w1s      = (float*)(pool + 41520);  // [24]
  float* sigs     = (float*)(pool + 41616);  // [24]
  float* qds      = (float*)(pool + 41712);  // [24]
  float* uss      = (float*)(pool + 41808);  // [24]
  float* qps      = (float*)(pool + 41904);  // [4][24] quad partials

  if (t < 32) msk[t>>4][t&15] = MSKT[(t&15)*NSAMP + n0 + (t>>4)];
  __syncthreads();

  // ---- Bd = dR1 ⊙ W1 (RNE bf16 split, coalesced W1 row read), thread t owns k=t ----
  {
    float w1r[24];
    #pragma unroll
    for (int d = 0; d < 24; ++d) w1r[d] = W1g[t*24 + d];
    float dr0 = ((msk[0][t>>5] >> (t&31)) & 1u) ? 1.f : -0.01f;
    float dr1 = ((msk[1][t>>5] >> (t&31)) & 1u) ? 1.f : -0.01f;
    #pragma unroll
    for (int c = 0; c < 48; ++c){
      int s = c >= 24, d = c - 24*s;
      float f = (s ? dr1 : dr0) * w1r[d];
      unsigned short h = f2b(f);
      BH[c*264 + t] = h;
      BL[c*264 + t] = f2b(f - b2f(h));
    }
  }
  __syncthreads();

  // ---- Stage D ----
  f32x4 accD[4][3];
  #pragma unroll
  for (int i = 0; i < 4; ++i)
    #pragma unroll
    for (int nt = 0; nt < 3; ++nt) accD[i][nt] = (f32x4){0.f,0.f,0.f,0.f};
  {
    const bf16x8* AHp = (const bf16x8*)(ws + OFF_W2FH);
    const bf16x8* ALp = (const bf16x8*)(ws + OFF_W2FL);
    for (int kb = 0; kb < 8; ++kb){
      bf16x8 AH[4], AL[4], BHf[3], BLf[3];
      #pragma unroll
      for (int i = 0; i < 4; ++i){
        int mt = 4*w + i;
        AH[i] = AHp[(mt*8+kb)*64 + l];
        AL[i] = ALp[(mt*8+kb)*64 + l];
      }
      #pragma unroll
      for (int nt = 0; nt < 3; ++nt){
        int off = (nt*16 + l15)*264 + kb*32 + l4g*8;
        BHf[nt] = *(const bf16x8*)(BH + off);
        BLf[nt] = *(const bf16x8*)(BL + off);
      }
      #pragma unroll
      for (int i = 0; i < 4; ++i)
        #pragma unroll
        for (int nt = 0; nt < 3; ++nt){
          accD[i][nt] = __builtin_amdgcn_mfma_f32_16x16x32_bf16(AH[i], BHf[nt], accD[i][nt], 0, 0, 0);
          accD[i][nt] = __builtin_amdgcn_mfma_f32_16x16x32_bf16(AH[i], BLf[nt], accD[i][nt], 0, 0, 0);
          accD[i][nt] = __builtin_amdgcn_mfma_f32_16x16x32_bf16(AL[i], BHf[nt], accD[i][nt], 0, 0, 0);
        }
    }
  }
  __syncthreads();

  // ---- epilogue D: scale by dR2, truncation split, store J2 over Bd ----
  #pragma unroll
  for (int i = 0; i < 4; ++i){
    int mt = 4*w + i;
    int m0 = mt*16 + 4*l4g;
    int bb = m0 & 31;
    #pragma unroll
    for (int nt = 0; nt < 3; ++nt){
      int c = nt*16 + l15;
      int s = c >= 24;
      unsigned word = msk[s][8 + (mt>>1)];
      unsigned uh[4], ul[4];
      #pragma unroll
      for (int r = 0; r < 4; ++r){
        float sc = ((word >> (bb + r)) & 1u) ? 1.f : -0.01f;
        float v = sc * accD[i][nt][r];
        unsigned uv = __float_as_uint(v);
        uh[r] = uv;
        float lo = v - __uint_as_float(uv & 0xFFFF0000u);
        ul[r] = __float_as_uint(lo);
      }
      *(uint2*)(BH + c*264 + m0) = make_uint2((uh[0]>>16) | (uh[1] & 0xFFFF0000u),
                                              (uh[2]>>16) | (uh[3] & 0xFFFF0000u));
      *(uint2*)(BL + c*264 + m0) = make_uint2((ul[0]>>16) | (ul[1] & 0xFFFF0000u),
                                              (ul[2]>>16) | (ul[3] & 0xFFFF0000u));
    }
  }
  __syncthreads();

  // ---- Stage E ----
  f32x4 accE[5][3];
  #pragma unroll
  for (int i = 0; i < 5; ++i)
    #pragma unroll
    for (int nt = 0; nt < 3; ++nt) accE[i][nt] = (f32x4){0.f,0.f,0.f,0.f};
  {
    const bf16x8* AHp = (const bf16x8*)(ws + OFF_WEFH);
    const bf16x8* ALp = (const bf16x8*)(ws + OFF_WEFL);
    for (int kb = 0; kb < 8; ++kb){
      bf16x8 AH[5], AL[5], BHf[3], BLf[3];
      #pragma unroll
      for (int i = 0; i < 5; ++i){
        int mt = 5*w + i;
        AH[i] = AHp[(mt*8+kb)*64 + l];
        AL[i] = ALp[(mt*8+kb)*64 + l];
      }
      #pragma unroll
      for (int nt = 0; nt < 3; ++nt){
        int off = (nt*16 + l15)*264 + kb*32 + l4g*8;
        BHf[nt] = *(const bf16x8*)(BH + off);
        BLf[nt] = *(const bf16x8*)(BL + off);
      }
      #pragma unroll
      for (int i = 0; i < 5; ++i)
        #pragma unroll
        for (int nt = 0; nt < 3; ++nt){
          accE[i][nt] = __builtin_amdgcn_mfma_f32_16x16x32_bf16(AH[i], BHf[nt], accE[i][nt], 0, 0, 0);
          accE[i][nt] = __builtin_amdgcn_mfma_f32_16x16x32_bf16(AH[i], BLf[nt], accE[i][nt], 0, 0, 0);
          accE[i][nt] = __builtin_amdgcn_mfma_f32_16x16x32_bf16(AL[i], BHf[nt], accE[i][nt], 0, 0, 0);
        }
    }
  }
  __syncthreads();   // pool free for tail overlay

  // ---- lean fused tails, sample-sequential ----
  for (int s = 0; s < 2; ++s){
    const int n = n0 + s;
    // P1: E-scatter + staging
    #pragma unroll
    for (int i = 0; i < 5; ++i){
      int mt = 5*w + i;
      #pragma unroll
      for (int nt = 0; nt < 3; ++nt){
        int c = nt*16 + l15;
        if ((c >= 24) == (s == 1)){
          int d = c - 24*s;
          #pragma unroll
          for (int r = 0; r < 4; ++r){
            int re = mt*16 + 4*l4g + r;
            if (re < 24) dld25[re*25 + d] = accE[i][nt][r];
            else if (re < 300) dlo_flat[(re-24)*24 + d] = accE[i][nt][r];
          }
        }
      }
    }
    for (int e = t; e < 576; e += 256){
      int a_ = e/24, b_ = e%24;
      int ma = (n*24 + a_) & (NSAMP-1);
      int mb_ = (n*24 + b_) & (NSAMP-1);
      qdm_s[a_*25 + b_] = q_dot[ma*24 + b_];
      um_s[a_*25 + b_]  = UT[a_*NSAMP + mb_];
    }
    if (t < 24){
      sigs[t] = SIGT[t*NSAMP + n];
      qds[t]  = q_dot[n*24 + t];
      uss[t]  = UT[t*NSAMP + n];
    }
    __syncthreads();

    // P2: dt partials (sequential b128) + dld_dt
    for (int k = t; k < 1656; k += 256){
      float4 v = *(const float4*)(dlo_flat + 4*k);
      int j4 = (k % 6)*4;
      qp2[k] = v.x*qds[j4] + v.y*qds[j4+1] + v.z*qds[j4+2] + v.w*qds[j4+3];
    }
    if (t < 24){
      float a = 0.f;
      #pragma unroll
      for (int d = 0; d < 24; ++d) a += dld25[t*25+d]*qds[d];
      dtld[t] = sigs[t]*a;
    }
    __syncthreads();

    // P3: dt reduce (grid-stride)
    for (int o = t; o < 276; o += 256){
      float a = 0.f;
      #pragma unroll
      for (int j = 0; j < 6; ++j) a += qp2[o*6+j];
      dtlo[o] = a;
    }
    __syncthreads();

    // P4: quad partials (t<96: 4 stripes x 24 i) || w1 (t in [128,152))
    if (t < 96){
      int g = t/24, i = t%24;
      float part = 0.f;
      for (int c2 = g; c2 < 24; c2 += 4){
        float v = qdm_s[i*25+c2]*sigs[c2]*dld25[c2*25+i];
        for (int r = c2+1; r < 24; ++r){
          int p = r*(r-1)/2 + c2;                 // faithful flat view: f = i*276 + p
          v += qdm_s[i*25+r]*dlo_flat[i*276 + p];
        }
        part += um_s[c2*25+i]*v;
      }
      qps[g*24 + i] = part;
    } else if (t >= 128 && t < 152){
      int i = t - 128;
      float a = qds[i]*dtld[i];
      for (int j = i+1; j < 24; ++j) a += qds[j]*dtlo[j*(j-1)/2 + i];
      w1s[i] = a;
    }
    __syncthreads();

    // P5: c
    if (t < 24){
      const int i = t;
      float cs = dtld[i]*uss[i] + LDT[i*NSAMP + n]*w1s[i];
      for (int k = 0; k < i; ++k){
        int p = i*(i-1)/2 + k;
        cs += LOT[p*NSAMP + n]*w1s[k] + dtlo[p]*uss[k];
      }
      float quad = qps[i] + qps[24+i] + qps[48+i] + qps[72+i];
      out[C_OFF + n*24 + i] = cs - quad;
    }
    __syncthreads();   // before next sample overwrites the overlay
  }
}

extern "C" void kernel_launch(void* const* d_in, const int* in_sizes, int n_in,
                              void* d_out, int out_size, void* d_ws, size_t ws_size,
                              hipStream_t stream)
{
  const float* q   = (const float*)d_in[0];
  const float* qd  = (const float*)d_in[1];
  const float* W1  = (const float*)d_in[2];
  const float* b1  = (const float*)d_in[3];
  const float* W2  = (const float*)d_in[4];
  const float* b2  = (const float*)d_in[5];
  const float* WG  = (const float*)d_in[6];
  const float* bG  = (const float*)d_in[7];
  const float* WLd = (const float*)d_in[8];
  const float* bLd = (const float*)d_in[9];
  const float* WLo = (const float*)d_in[10];
  const float* bLo = (const float*)d_in[11];
  float* out = (float*)d_out;
  float* ws  = (float*)d_ws;

  k0_prep<<<256, 256, 0, stream>>>(W1, W2, WG, WLd, WLo, ws);
  k1_fwd<<<NSAMP/16, 512, 0, stream>>>(q, qd, b1, b2, bG, bLd, bLo, ws, out);
  kDE<<<NSAMP/2, 256, 0, stream>>>(qd, W1, ws, out);
}

// Round 14
// 233.775 us; speedup vs baseline: 1.2035x; 1.0423x over previous
//
#include <hip/hip_runtime.h>
#include <math.h>

#define DIM 24
#define HID 256
#define NLO 276
#define NSAMP 4096
// output layout: M [4096*576] | c [4096*24] | g [4096*24]
#define C_OFF 2359296
#define G_OFF 2457600

// workspace layout (float offsets)
#define OFF_W2FH 0          // bf16 hi, W2 MFMA-A frags (65536 sh)   32768 f
#define OFF_W2FL 32768      // bf16 lo
#define OFF_WEFH 65536      // bf16 hi, [WLd;WLo;0] frags (81920 sh) 40960 f
#define OFF_WEFL 106496
#define OFF_W1H16 147456    // f16 hi, W1 frags (8192 sh)            4096 f
#define OFF_W1L16 151552
#define OFF_W2H16 155648    // f16 hi, W2 frags (65536 sh)           32768 f
#define OFF_W2L16 188416
#define OFF_WHH16 221184    // f16 hi, heads (Ld|G|Lo|0) frags       43008 f
#define OFF_WHL16 264192
// transposed per-sample fields [field][4096]
#define OFF_MSKT 307200     // 16 u32 words x 4096
#define OFF_SIGT 372736     // 24 x 4096
#define OFF_LDT  471040     // 24 x 4096
#define OFF_UT   569344     // 24 x 4096
#define OFF_LOT  667648     // 276 x 4096

typedef __attribute__((ext_vector_type(8))) short bf16x8;
typedef __attribute__((ext_vector_type(8))) _Float16 f16x8;
typedef __attribute__((ext_vector_type(4))) float f32x4;

__device__ __forceinline__ float leaky(float x){ return x > 0.f ? x : 0.01f*x; }
__device__ __forceinline__ unsigned short f2b(float f){           // fp32 -> bf16 RNE
  unsigned u = __float_as_uint(f);
  return (unsigned short)((u + 0x7FFFu + ((u >> 16) & 1u)) >> 16);
}
__device__ __forceinline__ float b2f(unsigned short h){ return __uint_as_float(((unsigned)h) << 16); }
__device__ __forceinline__ void f2h2(float v, unsigned short* hi, unsigned short* lo){
  _Float16 h = (_Float16)v;
  _Float16 l = (_Float16)((v - (float)h) * 4096.f);
  *hi = *(unsigned short*)&h; *lo = *(unsigned short*)&l;
}

// ---------------- Kernel 0: fragment packing ----------------
__global__ __launch_bounds__(256) void k0_prep(
    const float* __restrict__ W1, const float* __restrict__ W2,
    const float* __restrict__ WG, const float* __restrict__ WLd,
    const float* __restrict__ WLo, float* __restrict__ ws)
{
  const int tid = blockIdx.x*256 + threadIdx.x;
  const int nth = gridDim.x*256;
  unsigned short* W2FH = (unsigned short*)(ws + OFF_W2FH);
  unsigned short* W2FL = (unsigned short*)(ws + OFF_W2FL);
  for (int e = tid; e < 65536; e += nth){
    int j=e&7, l=(e>>3)&63, kb=(e>>9)&7, mt=e>>12;
    int m = mt*16+(l&15), k = kb*32+((l>>4)&3)*8+j;
    float v = W2[m*256+k];
    unsigned short h = f2b(v);
    W2FH[e]=h; W2FL[e]=f2b(v-b2f(h));
  }
  unsigned short* WEFH = (unsigned short*)(ws + OFF_WEFH);
  unsigned short* WEFL = (unsigned short*)(ws + OFF_WEFL);
  for (int e = tid; e < 81920; e += nth){
    int j=e&7, l=(e>>3)&63, kb=(e>>9)&7, mt=e>>12;
    int r = mt*16+(l&15), k = kb*32+((l>>4)&3)*8+j;
    float v = 0.f;
    if (r < 24) v = WLd[r*256+k]; else if (r < 300) v = WLo[(r-24)*256+k];
    unsigned short h = f2b(v);
    WEFH[e]=h; WEFL[e]=f2b(v-b2f(h));
  }
  unsigned short* W1H = (unsigned short*)(ws + OFF_W1H16);
  unsigned short* W1L = (unsigned short*)(ws + OFF_W1L16);
  for (int e = tid; e < 8192; e += nth){
    int j=e&7, l=(e>>3)&63, mt=e>>9;
    int m = mt*16+(l&15), k = ((l>>4)&3)*8+j;
    float v = (k < 24) ? W1[m*24+k] : 0.f;
    f2h2(v, &W1H[e], &W1L[e]);
  }
  unsigned short* W2H = (unsigned short*)(ws + OFF_W2H16);
  unsigned short* W2L = (unsigned short*)(ws + OFF_W2L16);
  for (int e = tid; e < 65536; e += nth){
    int j=e&7, l=(e>>3)&63, kb=(e>>9)&7, mt=e>>12;
    int m = mt*16+(l&15), k = kb*32+((l>>4)&3)*8+j;
    f2h2(W2[m*256+k], &W2H[e], &W2L[e]);
  }
  unsigned short* WHH = (unsigned short*)(ws + OFF_WHH16);
  unsigned short* WHL = (unsigned short*)(ws + OFF_WHL16);
  for (int e = tid; e < 86016; e += nth){
    int j=e&7, l=(e>>3)&63, kb=(e>>9)&7, mt=e>>12;
    int rr = mt*16+(l&15), k = kb*32+((l>>4)&3)*8+j;
    float v = 0.f;
    if (rr < 24) v = WLd[rr*256+k];
    else if (rr < 48) v = WG[(rr-24)*256+k];
    else if (rr < 324) v = WLo[(rr-48)*256+k];
    f2h2(v, &WHH[e], &WHL[e]);
  }
}

// ---------------- Kernel 1: MFMA forward + L/M/u (16 samples/block, 256 blocks, 512 thr) ----------------
__global__ __launch_bounds__(512) void k1_fwd(
    const float* __restrict__ q, const float* __restrict__ qd_g,
    const float* __restrict__ b1, const float* __restrict__ b2,
    const float* __restrict__ bG, const float* __restrict__ bLd,
    const float* __restrict__ bLo, float* __restrict__ ws,
    float* __restrict__ out)
{
  const int s0 = blockIdx.x*16, t = threadIdx.x;
  const int w = t>>6, l = t&63, l15 = l&15, l4g = (l>>4)&3;
  unsigned* MSKT = (unsigned*)(ws + OFF_MSKT);
  float* SIGT = ws + OFF_SIGT;
  float* LDT  = ws + OFF_LDT;
  float* UT   = ws + OFF_UT;
  float* LOT  = ws + OFF_LOT;

  __shared__ __align__(16) unsigned short pool[8448];  // BQ (1280 sh) -> BH2|BL2 (8448 sh)
  __shared__ unsigned char mb[16][64];
  __shared__ float qd_s[16][24];
  __shared__ float Lsm[16][600];         // per-sample L, stride 25
  unsigned short* BQH = pool;            // [16][40] f16
  unsigned short* BQL = BQH + 640;
  unsigned short* BH2 = pool;            // [16][264] f16
  unsigned short* BL2 = BH2 + 4224;

  if (t < 384){
    float v = q[s0*24 + t];
    int n = t/24, k = t%24;
    f2h2(v, &BQH[n*40+k], &BQL[n*40+k]);
    ((float*)qd_s)[t] = qd_g[s0*24 + t];
  }
  if (t < 256){ int n = t>>4, k = 24 + (t&15); BQH[n*40+k]=0; BQL[n*40+k]=0; }
  __syncthreads();

  // ---- phase A: h1 pre-acts = W1 @ qT (all 16 N-cols valid) ----
  f32x4 aH[2], aX[2];
  #pragma unroll
  for (int i=0;i<2;++i){ aH[i]=(f32x4){0,0,0,0}; aX[i]=(f32x4){0,0,0,0}; }
  {
    const f16x8* WH = (const f16x8*)(ws + OFF_W1H16);
    const f16x8* WL = (const f16x8*)(ws + OFF_W1L16);
    f16x8 Af[2], Al[2];
    #pragma unroll
    for (int i=0;i<2;++i){ int mt=w+8*i; Af[i]=WH[mt*64+l]; Al[i]=WL[mt*64+l]; }
    int off = l15*40 + l4g*8;
    f16x8 Bh = *(const f16x8*)(BQH+off), Bl = *(const f16x8*)(BQL+off);
    #pragma unroll
    for (int i=0;i<2;++i){
      aH[i]=__builtin_amdgcn_mfma_f32_16x16x32_f16(Af[i],Bh,aH[i],0,0,0);
      aX[i]=__builtin_amdgcn_mfma_f32_16x16x32_f16(Af[i],Bl,aX[i],0,0,0);
      aX[i]=__builtin_amdgcn_mfma_f32_16x16x32_f16(Al[i],Bh,aX[i],0,0,0);
    }
  }
  __syncthreads();
  #pragma unroll
  for (int i=0;i<2;++i){
    int m0=(w+8*i)*16+4*l4g;
    float4 bb = *(const float4*)(b1+m0);
    int n = l15;
    unsigned nib=0; unsigned short hs[4], ls[4];
    #pragma unroll
    for (int r=0;r<4;++r){
      float val = aH[i][r] + aX[i][r]*(1.f/4096.f) + ((const float*)&bb)[r];
      if (val > 0.f) nib |= 1u<<r;
      f2h2(leaky(val), &hs[r], &ls[r]);
    }
    mb[n][(m0>>2)] = (unsigned char)nib;
    *(uint2*)(BH2 + n*264 + m0) = make_uint2((unsigned)hs[0]|((unsigned)hs[1]<<16),
                                             (unsigned)hs[2]|((unsigned)hs[3]<<16));
    *(uint2*)(BL2 + n*264 + m0) = make_uint2((unsigned)ls[0]|((unsigned)ls[1]<<16),
                                             (unsigned)ls[2]|((unsigned)ls[3]<<16));
  }
  __syncthreads();
  if (t < 128){ // msk1 -> MSKT
    int n = t&15, w8 = t>>4; unsigned word = 0;
    #pragma unroll
    for (int b=0;b<8;++b) word |= (unsigned)(mb[n][w8*8+b] & 0xFu) << (4*b);
    MSKT[w8*NSAMP + s0+n] = word;
  }

  // ---- phase B: h2 = W2 @ h1 ----
  #pragma unroll
  for (int i=0;i<2;++i){ aH[i]=(f32x4){0,0,0,0}; aX[i]=(f32x4){0,0,0,0}; }
  {
    const f16x8* WH = (const f16x8*)(ws + OFF_W2H16);
    const f16x8* WL = (const f16x8*)(ws + OFF_W2L16);
    for (int kb=0;kb<8;++kb){
      f16x8 Af[2], Al[2];
      #pragma unroll
      for (int i=0;i<2;++i){ int mt=w+8*i; Af[i]=WH[(mt*8+kb)*64+l]; Al[i]=WL[(mt*8+kb)*64+l]; }
      int off = l15*264 + kb*32 + l4g*8;
      f16x8 Bh = *(const f16x8*)(BH2+off), Bl = *(const f16x8*)(BL2+off);
      #pragma unroll
      for (int i=0;i<2;++i){
        aH[i]=__builtin_amdgcn_mfma_f32_16x16x32_f16(Af[i],Bh,aH[i],0,0,0);
        aX[i]=__builtin_amdgcn_mfma_f32_16x16x32_f16(Af[i],Bl,aX[i],0,0,0);
        aX[i]=__builtin_amdgcn_mfma_f32_16x16x32_f16(Al[i],Bh,aX[i],0,0,0);
      }
    }
  }
  __syncthreads();
  #pragma unroll
  for (int i=0;i<2;++i){
    int m0=(w+8*i)*16+4*l4g;
    float4 bb = *(const float4*)(b2+m0);
    int n = l15;
    unsigned nib=0; unsigned short hs[4], ls[4];
    #pragma unroll
    for (int r=0;r<4;++r){
      float val = aH[i][r] + aX[i][r]*(1.f/4096.f) + ((const float*)&bb)[r];
      if (val > 0.f) nib |= 1u<<r;
      f2h2(leaky(val), &hs[r], &ls[r]);
    }
    mb[n][(m0>>2)] = (unsigned char)nib;
    *(uint2*)(BH2 + n*264 + m0) = make_uint2((unsigned)hs[0]|((unsigned)hs[1]<<16),
                                             (unsigned)hs[2]|((unsigned)hs[3]<<16));
    *(uint2*)(BL2 + n*264 + m0) = make_uint2((unsigned)ls[0]|((unsigned)ls[1]<<16),
                                             (unsigned)ls[2]|((unsigned)ls[3]<<16));
  }
  __syncthreads();
  if (t < 128){ // msk2 -> MSKT
    int n = t&15, w8 = t>>4; unsigned word = 0;
    #pragma unroll
    for (int b=0;b<8;++b) word |= (unsigned)(mb[n][w8*8+b] & 0xFu) << (4*b);
    MSKT[(8+w8)*NSAMP + s0+n] = word;
  }

  // ---- phase C: heads = [WLd;WG;WLo;0] @ h2 (21 M-tiles over 8 waves x 3 passes) ----
  for (int pass=0; pass<3; ++pass){
    int mt = w + 8*pass;
    bool act = (mt < 21);
    f32x4 cH=(f32x4){0,0,0,0}, cX=(f32x4){0,0,0,0};
    const f16x8* WH = (const f16x8*)(ws + OFF_WHH16);
    const f16x8* WL = (const f16x8*)(ws + OFF_WHL16);
    for (int kb=0;kb<8;++kb){
      f16x8 Af, Al;
      if (act){ Af=WH[(mt*8+kb)*64+l]; Al=WL[(mt*8+kb)*64+l]; }
      int off = l15*264 + kb*32 + l4g*8;
      f16x8 Bh = *(const f16x8*)(BH2+off), Bl = *(const f16x8*)(BL2+off);
      if (act){
        cH=__builtin_amdgcn_mfma_f32_16x16x32_f16(Af,Bh,cH,0,0,0);
        cX=__builtin_amdgcn_mfma_f32_16x16x32_f16(Af,Bl,cX,0,0,0);
        cX=__builtin_amdgcn_mfma_f32_16x16x32_f16(Al,Bh,cX,0,0,0);
      }
    }
    if (act){
      int m0 = mt*16+4*l4g;
      int n = l15, sG = s0+n;
      int tr = 0, tc = 0;
      if (m0 >= 48){
        int p = m0 - 48;
        tr = (int)((1.f + sqrtf(1.f + 8.f*(float)p))*0.5f);
        while (tr*(tr-1)/2 > p) --tr;
        while ((tr+1)*tr/2 <= p) ++tr;
        tc = p - tr*(tr-1)/2;
      }
      #pragma unroll
      for (int r=0;r<4;++r){
        int rr = m0+r;
        float val = cH[r] + cX[r]*(1.f/4096.f);
        if (rr < 24){
          val += bLd[rr];
          SIGT[rr*NSAMP + sG] = 1.f/(1.f + expf(-val));
          float sp = fmaxf(val,0.f) + log1pf(expf(-fabsf(val)));
          LDT[rr*NSAMP + sG] = sp;
          Lsm[n][rr*25 + rr] = sp;
        } else if (rr < 48){
          out[G_OFF + sG*24 + (rr-24)] = val + bG[rr-24];
        } else if (rr < 324){
          float lov = val + bLo[rr-48];
          LOT[(rr-48)*NSAMP + sG] = lov;
          Lsm[n][tr*25 + tc] = lov;
          if (++tc == tr){ ++tr; tc = 0; }
        }
      }
    }
  }
  __syncthreads();

  // ---- M = L L^T + 1e-9 I (16 samples) ----
  for (int n2 = 0; n2 < 16; ++n2){
    const float* Ls = Lsm[n2];
    for (int e = t; e < 576; e += 512){
      int r = e/24, c = e%24, km = min(r,c);
      float acc = (r == c) ? 1e-9f : 0.f;
      for (int k = 0; k <= km; ++k) acc += Ls[r*25+k]*Ls[c*25+k];
      out[(size_t)(s0+n2)*576 + e] = acc;
    }
  }
  // ---- u[c] = qd[c]*L[c,c] + sum_{r>c} qd[r]*L[r,c] ----
  if (t < 384){
    int n = t/24, c = t%24;
    float u = qd_s[n][c]*Lsm[n][c*25+c];
    for (int r = c+1; r < 24; ++r) u += qd_s[n][r]*Lsm[n][r*25+c];
    UT[c*NSAMP + s0+n] = u;
  }
}

// ---------------- Kernel DE: MFMA Jacobian GEMMs + lean tails (2 samples/block) ----------------
__global__ __launch_bounds__(256, 3) void kDE(
    const float* __restrict__ q_dot, const float* __restrict__ W1g,
    float* __restrict__ ws, float* __restrict__ out)
{
  const int n0 = blockIdx.x*2, t = threadIdx.x;
  const int w = t >> 6, l = t & 63;
  const int l15 = l & 15, l4g = (l >> 4) & 3;
  const unsigned* MSKT = (const unsigned*)(ws + OFF_MSKT);
  const float* SIGT = ws + OFF_SIGT;
  const float* LDT  = ws + OFF_LDT;
  const float* UT   = ws + OFF_UT;
  const float* LOT  = ws + OFF_LOT;

  // pool: [BH|BL] bf16 (50688 B) during GEMMs; tail overlay after
  __shared__ __align__(16) char pool[50688];
  __shared__ unsigned msk[2][16];
  unsigned short* BH = (unsigned short*)pool;
  unsigned short* BL = BH + 12672;
  // tail overlay
  float* dlo_flat = (float*)pool;            // [276*24] flat (faithful view) 26496 B
  float* dld25    = (float*)(pool + 26496);  // [24][25]
  float* qdm_s    = (float*)(pool + 28896);  // [24][25]
  float* um_s     = (float*)(pool + 31296);  // [24][25]
  float* qp2      = (float*)(pool + 33696);  // [1656] dt partials
  float* dtlo     = (float*)(pool + 40320);  // [276]
  float* dtld     = (float*)(pool + 41424);  // [24]
  float* w1s      = (float*)(pool + 41520);  // [24]
  float* sigs     = (float*)(pool + 41616);  // [24]
  float* qds      = (float*)(pool + 41712);  // [24]
  float* uss      = (float*)(pool + 41808);  // [24]
  float* qps      = (float*)(pool + 41904);  // [4][24] quad partials
  float* qp3      = (float*)(pool + 42288);  // [1656] quad flat partials
  unsigned char* rT = (unsigned char*)(pool + 48912);  // [276] tri row
  unsigned char* cT = (unsigned char*)(pool + 49188);  // [276] tri col

  if (t < 32) msk[t>>4][t&15] = MSKT[(t&15)*NSAMP + n0 + (t>>4)];
  __syncthreads();

  // ---- Bd = dR1 ⊙ W1 (RNE bf16 split, coalesced W1 row read), thread t owns k=t ----
  {
    float w1r[24];
    #pragma unroll
    for (int d = 0; d < 24; ++d) w1r[d] = W1g[t*24 + d];
    float dr0 = ((msk[0][t>>5] >> (t&31)) & 1u) ? 1.f : -0.01f;
    float dr1 = ((msk[1][t>>5] >> (t&31)) & 1u) ? 1.f : -0.01f;
    #pragma unroll
    for (int c = 0; c < 48; ++c){
      int s = c >= 24, d = c - 24*s;
      float f = (s ? dr1 : dr0) * w1r[d];
      unsigned short h = f2b(f);
      BH[c*264 + t] = h;
      BL[c*264 + t] = f2b(f - b2f(h));
    }
  }
  __syncthreads();

  // ---- Stage D ----
  f32x4 accD[4][3];
  #pragma unroll
  for (int i = 0; i < 4; ++i)
    #pragma unroll
    for (int nt = 0; nt < 3; ++nt) accD[i][nt] = (f32x4){0.f,0.f,0.f,0.f};
  {
    const bf16x8* AHp = (const bf16x8*)(ws + OFF_W2FH);
    const bf16x8* ALp = (const bf16x8*)(ws + OFF_W2FL);
    for (int kb = 0; kb < 8; ++kb){
      bf16x8 AH[4], AL[4], BHf[3], BLf[3];
      #pragma unroll
      for (int i = 0; i < 4; ++i){
        int mt = 4*w + i;
        AH[i] = AHp[(mt*8+kb)*64 + l];
        AL[i] = ALp[(mt*8+kb)*64 + l];
      }
      #pragma unroll
      for (int nt = 0; nt < 3; ++nt){
        int off = (nt*16 + l15)*264 + kb*32 + l4g*8;
        BHf[nt] = *(const bf16x8*)(BH + off);
        BLf[nt] = *(const bf16x8*)(BL + off);
      }
      #pragma unroll
      for (int i = 0; i < 4; ++i)
        #pragma unroll
        for (int nt = 0; nt < 3; ++nt){
          accD[i][nt] = __builtin_amdgcn_mfma_f32_16x16x32_bf16(AH[i], BHf[nt], accD[i][nt], 0, 0, 0);
          accD[i][nt] = __builtin_amdgcn_mfma_f32_16x16x32_bf16(AH[i], BLf[nt], accD[i][nt], 0, 0, 0);
          accD[i][nt] = __builtin_amdgcn_mfma_f32_16x16x32_bf16(AL[i], BHf[nt], accD[i][nt], 0, 0, 0);
        }
    }
  }
  __syncthreads();

  // ---- epilogue D: scale by dR2, truncation split, store J2 over Bd ----
  #pragma unroll
  for (int i = 0; i < 4; ++i){
    int mt = 4*w + i;
    int m0 = mt*16 + 4*l4g;
    int bb = m0 & 31;
    #pragma unroll
    for (int nt = 0; nt < 3; ++nt){
      int c = nt*16 + l15;
      int s = c >= 24;
      unsigned word = msk[s][8 + (mt>>1)];
      unsigned uh[4], ul[4];
      #pragma unroll
      for (int r = 0; r < 4; ++r){
        float sc = ((word >> (bb + r)) & 1u) ? 1.f : -0.01f;
        float v = sc * accD[i][nt][r];
        unsigned uv = __float_as_uint(v);
        uh[r] = uv;
        float lo = v - __uint_as_float(uv & 0xFFFF0000u);
        ul[r] = __float_as_uint(lo);
      }
      *(uint2*)(BH + c*264 + m0) = make_uint2((uh[0]>>16) | (uh[1] & 0xFFFF0000u),
                                              (uh[2]>>16) | (uh[3] & 0xFFFF0000u));
      *(uint2*)(BL + c*264 + m0) = make_uint2((ul[0]>>16) | (ul[1] & 0xFFFF0000u),
                                              (ul[2]>>16) | (ul[3] & 0xFFFF0000u));
    }
  }
  __syncthreads();

  // ---- Stage E ----
  f32x4 accE[5][3];
  #pragma unroll
  for (int i = 0; i < 5; ++i)
    #pragma unroll
    for (int nt = 0; nt < 3; ++nt) accE[i][nt] = (f32x4){0.f,0.f,0.f,0.f};
  {
    const bf16x8* AHp = (const bf16x8*)(ws + OFF_WEFH);
    const bf16x8* ALp = (const bf16x8*)(ws + OFF_WEFL);
    for (int kb = 0; kb < 8; ++kb){
      bf16x8 AH[5], AL[5], BHf[3], BLf[3];
      #pragma unroll
      for (int i = 0; i < 5; ++i){
        int mt = 5*w + i;
        AH[i] = AHp[(mt*8+kb)*64 + l];
        AL[i] = ALp[(mt*8+kb)*64 + l];
      }
      #pragma unroll
      for (int nt = 0; nt < 3; ++nt){
        int off = (nt*16 + l15)*264 + kb*32 + l4g*8;
        BHf[nt] = *(const bf16x8*)(BH + off);
        BLf[nt] = *(const bf16x8*)(BL + off);
      }
      #pragma unroll
      for (int i = 0; i < 5; ++i)
        #pragma unroll
        for (int nt = 0; nt < 3; ++nt){
          accE[i][nt] = __builtin_amdgcn_mfma_f32_16x16x32_bf16(AH[i], BHf[nt], accE[i][nt], 0, 0, 0);
          accE[i][nt] = __builtin_amdgcn_mfma_f32_16x16x32_bf16(AH[i], BLf[nt], accE[i][nt], 0, 0, 0);
          accE[i][nt] = __builtin_amdgcn_mfma_f32_16x16x32_bf16(AL[i], BHf[nt], accE[i][nt], 0, 0, 0);
        }
    }
  }
  __syncthreads();   // pool free for tail overlay

  // ---- tri decode tables (once per block; region disjoint from P1 writes) ----
  for (int p = t; p < 276; p += 256){
    int r = (int)((1.f + sqrtf(1.f + 8.f*(float)p))*0.5f);
    while (r*(r-1)/2 > p) --r;
    while ((r+1)*r/2 <= p) ++r;
    rT[p] = (unsigned char)r;
    cT[p] = (unsigned char)(p - r*(r-1)/2);
  }

  // ---- lean fused tails, sample-sequential ----
  for (int s = 0; s < 2; ++s){
    const int n = n0 + s;
    // P1: E-scatter + staging
    #pragma unroll
    for (int i = 0; i < 5; ++i){
      int mt = 5*w + i;
      #pragma unroll
      for (int nt = 0; nt < 3; ++nt){
        int c = nt*16 + l15;
        if ((c >= 24) == (s == 1)){
          int d = c - 24*s;
          #pragma unroll
          for (int r = 0; r < 4; ++r){
            int re = mt*16 + 4*l4g + r;
            if (re < 24) dld25[re*25 + d] = accE[i][nt][r];
            else if (re < 300) dlo_flat[(re-24)*24 + d] = accE[i][nt][r];
          }
        }
      }
    }
    for (int e = t; e < 576; e += 256){
      int a_ = e/24, b_ = e%24;
      int ma = (n*24 + a_) & (NSAMP-1);
      int mb_ = (n*24 + b_) & (NSAMP-1);
      qdm_s[a_*25 + b_] = q_dot[ma*24 + b_];
      um_s[a_*25 + b_]  = UT[a_*NSAMP + mb_];
    }
    if (t < 24){
      sigs[t] = SIGT[t*NSAMP + n];
      qds[t]  = q_dot[n*24 + t];
      uss[t]  = UT[t*NSAMP + n];
    }
    __syncthreads();

    // P2: dt partials (sequential b128) + dld_dt
    for (int k = t; k < 1656; k += 256){
      float4 v = *(const float4*)(dlo_flat + 4*k);
      int j4 = (k % 6)*4;
      qp2[k] = v.x*qds[j4] + v.y*qds[j4+1] + v.z*qds[j4+2] + v.w*qds[j4+3];
    }
    if (t < 24){
      float a = 0.f;
      #pragma unroll
      for (int d = 0; d < 24; ++d) a += dld25[t*25+d]*qds[d];
      dtld[t] = sigs[t]*a;
    }
    __syncthreads();

    // P3: dt reduce (grid-stride)
    for (int o = t; o < 276; o += 256){
      float a = 0.f;
      #pragma unroll
      for (int j = 0; j < 6; ++j) a += qp2[o*6+j];
      dtlo[o] = a;
    }
    __syncthreads();

    // P4a: quad flat partials — j4-fastest => conflict-free sequential b128
    for (int k = t; k < 1656; k += 256){
      int i = k/69, j4 = k - i*69, p = 4*j4;
      float4 v = *(const float4*)(dlo_flat + i*276 + p);
      float s0 = v.x * qdm_s[i*25 + rT[p+0]] * um_s[cT[p+0]*25 + i];
      float s1 = v.y * qdm_s[i*25 + rT[p+1]] * um_s[cT[p+1]*25 + i];
      float s2 = v.z * qdm_s[i*25 + rT[p+2]] * um_s[cT[p+2]*25 + i];
      float s3 = v.w * qdm_s[i*25 + rT[p+3]] * um_s[cT[p+3]*25 + i];
      qp3[k] = (s0+s1)+(s2+s3);
    }
    __syncthreads();

    // P4b: quad reduce (96 thr; g==0 folds the diag term) || w1 (t in [128,152))
    if (t < 96){
      int g = t/24, i = t%24;
      float a = 0.f;
      for (int j4 = g; j4 < 69; j4 += 4) a += qp3[i*69 + j4];
      if (g == 0){
        #pragma unroll
        for (int c2 = 0; c2 < 24; ++c2)
          a += um_s[c2*25+i]*qdm_s[i*25+c2]*sigs[c2]*dld25[c2*25+i];
      }
      qps[g*24 + i] = a;
    } else if (t >= 128 && t < 152){
      int i = t - 128;
      float a = qds[i]*dtld[i];
      for (int j = i+1; j < 24; ++j) a += qds[j]*dtlo[j*(j-1)/2 + i];
      w1s[i] = a;
    }
    __syncthreads();

    // P5: c
    if (t < 24){
      const int i = t;
      float cs = dtld[i]*uss[i] + LDT[i*NSAMP + n]*w1s[i];
      for (int k = 0; k < i; ++k){
        int p = i*(i-1)/2 + k;
        cs += LOT[p*NSAMP + n]*w1s[k] + dtlo[p]*uss[k];
      }
      float quad = qps[i] + qps[24+i] + qps[48+i] + qps[72+i];
      out[C_OFF + n*24 + i] = cs - quad;
    }
    __syncthreads();   // before next sample overwrites the overlay
  }
}

extern "C" void kernel_launch(void* const* d_in, const int* in_sizes, int n_in,
                              void* d_out, int out_size, void* d_ws, size_t ws_size,
                              hipStream_t stream)
{
  const float* q   = (const float*)d_in[0];
  const float* qd  = (const float*)d_in[1];
  const float* W1  = (const float*)d_in[2];
  const float* b1  = (const float*)d_in[3];
  const float* W2  = (const float*)d_in[4];
  const float* b2  = (const float*)d_in[5];
  const float* WG  = (const float*)d_in[6];
  const float* bG  = (const float*)d_in[7];
  const float* WLd = (const float*)d_in[8];
  const float* bLd = (const float*)d_in[9];
  const float* WLo = (const float*)d_in[10];
  const float* bLo = (const float*)d_in[11];
  float* out = (float*)d_out;
  float* ws  = (float*)d_ws;

  k0_prep<<<256, 256, 0, stream>>>(W1, W2, WG, WLd, WLo, ws);
  k1_fwd<<<NSAMP/16, 512, 0, stream>>>(q, qd, b1, b2, bG, bLd, bLo, ws, out);
  kDE<<<NSAMP/2, 256, 0, stream>>>(qd, W1, ws, out);
}